// Round 1
// baseline (452.818 us; speedup 1.0000x reference)
//
#include <hip/hip_runtime.h>
#include <math.h>

#define QLEN 1024
#define MLEN 1024
#define KLEN 2048
#define BSZc 2
#define NH 16
#define DH 64
#define DM 1024
#define DI 4096

typedef unsigned short ushort_t;
typedef __attribute__((ext_vector_type(8))) short short8;
typedef __attribute__((ext_vector_type(4))) float f32x4;

__device__ __forceinline__ ushort_t f2bf(float x) {
    unsigned int u = __float_as_uint(x);
    unsigned int r = (u + 0x7FFFu + ((u >> 16) & 1u)) >> 16;
    return (ushort_t)r;
}

__device__ __forceinline__ void gload_lds16(const ushort_t* g, ushort_t* l) {
    __builtin_amdgcn_global_load_lds(
        (const __attribute__((address_space(1))) unsigned int*)g,
        (__attribute__((address_space(3))) unsigned int*)l,
        16, 0, 0);
}

// ---------------------------------------------------------------------------
// segmented f32 -> bf16 casts (one launch per phase)
// ---------------------------------------------------------------------------
__device__ __forceinline__ void cast8(const float* s, ushort_t* d, int g) {
    const float4 a = *(const float4*)(s + g * 8);
    const float4 b = *(const float4*)(s + g * 8 + 4);
    short8 o;
    o[0] = (short)f2bf(a.x); o[1] = (short)f2bf(a.y);
    o[2] = (short)f2bf(a.z); o[3] = (short)f2bf(a.w);
    o[4] = (short)f2bf(b.x); o[5] = (short)f2bf(b.y);
    o[6] = (short)f2bf(b.z); o[7] = (short)f2bf(b.w);
    *(short8*)(d + g * 8) = o;
}

__global__ __launch_bounds__(256)
void cast_phase1(const float* __restrict__ qkv_w, const float* __restrict__ rnet_w,
                 const float* __restrict__ mems, const float* __restrict__ w,
                 const float* __restrict__ r,
                 ushort_t* __restrict__ W1, ushort_t* __restrict__ W2,
                 ushort_t* __restrict__ Acat, ushort_t* __restrict__ Rsrc)
{
    int g = blockIdx.x * 256 + threadIdx.x;
    if (g < 393216)            { cast8(qkv_w,  W1,              g); }
    else if (g < 524288)       { cast8(rnet_w, W2,              g - 393216); }
    else if (g < 786432)       { cast8(mems,   Acat,            g - 524288); }
    else if (g < 1048576)      { cast8(w,      Acat + 2097152,  g - 786432); }
    else if (g < 1310720)      { cast8(r,      Rsrc,            g - 1048576); }
}

__global__ __launch_bounds__(256)
void cast_phase2(const float* __restrict__ o_w, const float* __restrict__ ffw1,
                 const float* __restrict__ ffw2,
                 ushort_t* __restrict__ W3, ushort_t* __restrict__ W4,
                 ushort_t* __restrict__ W5)
{
    int g = blockIdx.x * 256 + threadIdx.x;
    if (g < 131072)            { cast8(o_w,  W3, g); }
    else if (g < 655360)       { cast8(ffw1, W4, g - 131072); }
    else if (g < 1179648)      { cast8(ffw2, W5, g - 655360); }
}

// ---------------------------------------------------------------------------
// bf16 MFMA GEMM: C = A @ B^T. 128 x BN tile, BK=64 (two BK=32 buffer pairs).
// SPLIT>1: blockIdx.z selects K-slice; partial f32 out; bias only on z==0.
// EMODE 0: f32 out (+bias). EMODE 3: bf16 out (+bias, +relu if ACT).
// ---------------------------------------------------------------------------
template<int EMODE, int ACT, int BN, int SPLIT>
__global__ __launch_bounds__(256)
void gemm_mfma(const ushort_t* __restrict__ A, const ushort_t* __restrict__ B,
               const float* __restrict__ bias,
               void* __restrict__ O0v, void* __restrict__ O1v,
               int M, int N, int Ks, int lda, int ldb)
{
    constexpr int JT = BN / 32;
    __shared__ ushort_t At0[128 * 32];
    __shared__ ushort_t At1[128 * 32];
    __shared__ ushort_t Bt0[BN * 32];
    __shared__ ushort_t Bt1[BN * 32];

    const int tid  = threadIdx.x;
    const int lane = tid & 63;
    const int w    = tid >> 6;
    const int lr   = lane & 15;
    const int quad = lane >> 4;
    const int m0   = blockIdx.x * 128;
    const int n0   = blockIdx.y * BN;
    const int z    = (SPLIT > 1) ? (int)blockIdx.z : 0;
    const int kbase = z * Ks;
    const int wm0  = (w >> 1) * 64;
    const int wn0  = (w & 1) * (BN / 2);

    f32x4 acc[4][JT];
#pragma unroll
    for (int it = 0; it < 4; ++it)
#pragma unroll
        for (int jt = 0; jt < JT; ++jt) acc[it][jt] = (f32x4){0.f, 0.f, 0.f, 0.f};

    const int srow = lane >> 2;
    const int scol = (lane & 3) << 3;
    const ushort_t* Ag = A + (size_t)(m0 + w * 32 + srow) * lda + kbase + scol;
    ushort_t* a00 = At0 + (w * 32) * 32;
    ushort_t* a01 = At0 + (w * 32 + 16) * 32;
    ushort_t* a10 = At1 + (w * 32) * 32;
    ushort_t* a11 = At1 + (w * 32 + 16) * 32;
    const ushort_t* Bg;
    ushort_t *b00, *b01 = nullptr, *b10, *b11 = nullptr;
    if (BN == 128) {
        Bg  = B + (size_t)(n0 + w * 32 + srow) * ldb + kbase + scol;
        b00 = Bt0 + (w * 32) * 32;
        b01 = Bt0 + (w * 32 + 16) * 32;
        b10 = Bt1 + (w * 32) * 32;
        b11 = Bt1 + (w * 32 + 16) * 32;
    } else {
        Bg  = B + (size_t)(n0 + w * 16 + srow) * ldb + kbase + scol;
        b00 = Bt0 + (w * 16) * 32;
        b10 = Bt1 + (w * 16) * 32;
    }

    const ushort_t* Ato0 = At0 + (wm0 + lr) * 32 + quad * 8;
    const ushort_t* Ato1 = At1 + (wm0 + lr) * 32 + quad * 8;
    const ushort_t* Bto0 = Bt0 + (wn0 + lr) * 32 + quad * 8;
    const ushort_t* Bto1 = Bt1 + (wn0 + lr) * 32 + quad * 8;

    for (int k0 = 0; k0 < Ks; k0 += 64) {
        __syncthreads();
        gload_lds16(Ag + k0, a00);
        gload_lds16(Ag + (size_t)16 * lda + k0, a01);
        gload_lds16(Ag + k0 + 32, a10);
        gload_lds16(Ag + (size_t)16 * lda + k0 + 32, a11);
        if (BN == 128) {
            gload_lds16(Bg + k0, b00);
            gload_lds16(Bg + (size_t)16 * ldb + k0, b01);
            gload_lds16(Bg + k0 + 32, b10);
            gload_lds16(Bg + (size_t)16 * ldb + k0 + 32, b11);
        } else {
            gload_lds16(Bg + k0, b00);
            gload_lds16(Bg + k0 + 32, b10);
        }
        __syncthreads();

        short8 af[4], bf[JT];
#pragma unroll
        for (int it = 0; it < 4; ++it)
            af[it] = *(const short8*)(Ato0 + it * 16 * 32);
#pragma unroll
        for (int jt = 0; jt < JT; ++jt)
            bf[jt] = *(const short8*)(Bto0 + jt * 16 * 32);
#pragma unroll
        for (int it = 0; it < 4; ++it)
#pragma unroll
            for (int jt = 0; jt < JT; ++jt)
                acc[it][jt] = __builtin_amdgcn_mfma_f32_16x16x32_bf16(
                    af[it], bf[jt], acc[it][jt], 0, 0, 0);
#pragma unroll
        for (int it = 0; it < 4; ++it)
            af[it] = *(const short8*)(Ato1 + it * 16 * 32);
#pragma unroll
        for (int jt = 0; jt < JT; ++jt)
            bf[jt] = *(const short8*)(Bto1 + jt * 16 * 32);
#pragma unroll
        for (int it = 0; it < 4; ++it)
#pragma unroll
            for (int jt = 0; jt < JT; ++jt)
                acc[it][jt] = __builtin_amdgcn_mfma_f32_16x16x32_bf16(
                    af[it], bf[jt], acc[it][jt], 0, 0, 0);
    }

#pragma unroll
    for (int it = 0; it < 4; ++it)
#pragma unroll
        for (int jt = 0; jt < JT; ++jt)
#pragma unroll
            for (int rg = 0; rg < 4; ++rg) {
                const int m = m0 + wm0 + it * 16 + quad * 4 + rg;
                const int n = n0 + wn0 + jt * 16 + lr;
                float v = acc[it][jt][rg];
                if (EMODE == 0) {
                    float* dst = (float*)(z ? O1v : O0v);
                    if (bias && z == 0) v += bias[n];
                    dst[(size_t)m * N + n] = v;
                } else {
                    v += bias[n];
                    if (ACT == 1) v = fmaxf(v, 0.f);
                    ((ushort_t*)O0v)[(size_t)m * N + n] = f2bf(v);
                }
            }
}

// ---------------------------------------------------------------------------
// Fused QKV + r_net GEMM (BK=32 — known good).
// ---------------------------------------------------------------------------
__global__ __launch_bounds__(256)
void gemm_qkvr(const ushort_t* __restrict__ Acat, const ushort_t* __restrict__ W1,
               const ushort_t* __restrict__ Rsrc, const ushort_t* __restrict__ W2,
               ushort_t* __restrict__ Qac, ushort_t* __restrict__ Qbd,
               ushort_t* __restrict__ Kbf, ushort_t* __restrict__ Vtb,
               ushort_t* __restrict__ Rh,
               const float* __restrict__ rwb, const float* __restrict__ rrb)
{
    __shared__ ushort_t At[128 * 32];
    __shared__ ushort_t Bt[128 * 32];

    const int bid  = blockIdx.x;
    const bool isr = bid >= 768;
    const ushort_t* A; const ushort_t* B; int m0, n0;
    if (!isr) { A = Acat; B = W1; m0 = (bid & 31) * 128; n0 = (bid >> 5) * 128; }
    else { int t = bid - 768; A = Rsrc; B = W2; m0 = (t & 15) * 128; n0 = (t >> 4) * 128; }
    const int K = 1024;

    const int tid  = threadIdx.x;
    const int lane = tid & 63;
    const int w    = tid >> 6;
    const int lr   = lane & 15;
    const int quad = lane >> 4;
    const int wm0  = (w >> 1) * 64;
    const int wn0  = (w & 1) * 64;

    f32x4 acc[4][4];
#pragma unroll
    for (int it = 0; it < 4; ++it)
#pragma unroll
        for (int jt = 0; jt < 4; ++jt) acc[it][jt] = (f32x4){0.f, 0.f, 0.f, 0.f};

    const int srow = lane >> 2;
    const int scol = (lane & 3) << 3;
    const ushort_t* Ag = A + (size_t)(m0 + w * 32 + srow) * K + scol;
    const ushort_t* Bg = B + (size_t)(n0 + w * 32 + srow) * K + scol;
    ushort_t* lA0 = At + (w * 32) * 32;
    ushort_t* lA1 = At + (w * 32 + 16) * 32;
    ushort_t* lB0 = Bt + (w * 32) * 32;
    ushort_t* lB1 = Bt + (w * 32 + 16) * 32;

    const ushort_t* Ato = At + (wm0 + lr) * 32 + quad * 8;
    const ushort_t* Bto = Bt + (wn0 + lr) * 32 + quad * 8;

    for (int k0 = 0; k0 < K; k0 += 32) {
        __syncthreads();
        gload_lds16(Ag + k0, lA0);
        gload_lds16(Ag + (size_t)16 * K + k0, lA1);
        gload_lds16(Bg + k0, lB0);
        gload_lds16(Bg + (size_t)16 * K + k0, lB1);
        __syncthreads();

        short8 af[4], bf[4];
#pragma unroll
        for (int it = 0; it < 4; ++it)
            af[it] = *(const short8*)(Ato + it * 16 * 32);
#pragma unroll
        for (int jt = 0; jt < 4; ++jt)
            bf[jt] = *(const short8*)(Bto + jt * 16 * 32);
#pragma unroll
        for (int it = 0; it < 4; ++it)
#pragma unroll
            for (int jt = 0; jt < 4; ++jt)
                acc[it][jt] = __builtin_amdgcn_mfma_f32_16x16x32_bf16(
                    af[it], bf[jt], acc[it][jt], 0, 0, 0);
    }

#pragma unroll
    for (int it = 0; it < 4; ++it)
#pragma unroll
        for (int jt = 0; jt < 4; ++jt)
#pragma unroll
            for (int rg = 0; rg < 4; ++rg) {
                const int m = m0 + wm0 + it * 16 + quad * 4 + rg;
                const int n = n0 + wn0 + jt * 16 + lr;
                const float v = acc[it][jt][rg];
                if (!isr) {
                    const int j = m >> 1, b = m & 1;
                    const int part = n >> 10, hh = (n >> 6) & 15, d = n & 63;
                    if (part == 0) {
                        if (j >= MLEN) {
                            const int qi = j - MLEN;
                            const size_t qidx = (((size_t)(b * NH + hh)) * QLEN + qi) * DH + d;
                            Qac[qidx] = f2bf(v + rwb[hh * DH + d]);
                            Qbd[qidx] = f2bf(v + rrb[hh * DH + d]);
                        }
                    } else if (part == 1) {
                        Kbf[(((size_t)(b * NH + hh)) * KLEN + j) * DH + d] = f2bf(v);
                    } else {
                        Vtb[(((size_t)(b * NH + hh)) * DH + d) * KLEN + j] = f2bf(v);
                    }
                } else {
                    const int hh = n >> 6, d = n & 63;
                    Rh[(((size_t)hh) * KLEN + m) * DH + d] = f2bf(v);
                }
            }
}

// ---------------------------------------------------------------------------
// MFMA flash attention with TransformerXL rel-shift, split-K x2 (contiguous
// halves so the R window slides 64/chunk -> ring buffer).
//
// Round-8 restructure (T14 async-STAGE pipeline):
//  * V^T PV-fragments are REGISTER-prefetched per wave at chunk top (32 VGPR)
//    and consumed after softmax — no V LDS staging, no Bw overlay, barrier D
//    eliminated (3 -> 2 barriers/chunk).
//  * K chunk + new R ring rows are register-prefetched ONE CHUNK AHEAD and
//    ds-written at the next chunk top: steady-state exposed global latency ~0.
//  LDS = Kt(9216) + Rt ring(18432) + Bw f32(21504) = 49152 B -> 3 blocks/CU.
// ---------------------------------------------------------------------------
__global__ __launch_bounds__(256, 3)
void attn_mfma(const ushort_t* __restrict__ Qac, const ushort_t* __restrict__ Qbd,
               const ushort_t* __restrict__ Kb, const ushort_t* __restrict__ Vt,
               const ushort_t* __restrict__ Rb,
               float* __restrict__ Op0, float* __restrict__ Op1,
               float* __restrict__ Mp, float* __restrict__ Lp)
{
    __shared__ __align__(16) ushort_t Kt[64 * 72];     //  9216 B
    __shared__ __align__(16) ushort_t Rt[128 * 72];    // 18432 B, ring
    __shared__ __align__(16) float    Bw[4][16][84];   // 21504 B

    const int tid  = threadIdx.x;
    const int lane = tid & 63;
    const int w    = tid >> 6;
    const int lr   = lane & 15;
    const int quad = lane >> 4;
    const int qt   = blockIdx.x;
    const int s    = blockIdx.y;
    const int bh   = blockIdx.z;
    const int i0   = qt << 6;
    const int h    = bh & 15;
    const int b    = bh >> 4;

    short8 qaf[2], qbf[2];
    {
        const size_t rowoff = ((size_t)bh * QLEN + i0 + w * 16 + lr) * DH;
#pragma unroll
        for (int kt = 0; kt < 2; ++kt) {
            qaf[kt] = *(const short8*)(Qac + rowoff + kt * 32 + quad * 8);
            qbf[kt] = *(const short8*)(Qbd + rowoff + kt * 32 + quad * 8);
        }
    }

    f32x4 O[4];
#pragma unroll
    for (int nt = 0; nt < 4; ++nt) O[nt] = (f32x4){0.f, 0.f, 0.f, 0.f};
    float m_run = -3.4e38f, l_run = 0.f;

    const int nc   = qt + 17;
    const int half = (nc + 1) >> 1;
    const int c_lo = s ? half : 0;
    const int c_hi = s ? nc : half;
    const int stw  = 3 - w;
    const float SC = 0.125f * 1.44269504f;   // scale * log2(e)
    const ushort_t* Kh  = Kb + (size_t)bh * KLEN * DH;
    const ushort_t* Vh  = Vt + (size_t)bh * DH * KLEN;
    const ushort_t* Rhp = Rb + (size_t)h * KLEN * DH;

    // per-thread staging coordinates (identical tiling to the old f-loop)
    const int srow = tid >> 3;           // 0..31; rows srow, srow+32
    const int scol = (tid & 7) << 3;     // element col (16 B granule)

    // --- prologue: register-prefetch K[c_lo] + full initial R window ---
    int4 kpf[2], rpf[4];
    {
        const int j0 = c_lo << 6;
        kpf[0] = *(const int4*)(Kh + (size_t)(j0 + srow) * DH + scol);
        kpf[1] = *(const int4*)(Kh + (size_t)(j0 + srow + 32) * DH + scol);
        const int wb = 960 - i0 + j0;
#pragma unroll
        for (int t = 0; t < 4; ++t) {
            int g = wb + srow + t * 32;
            int gc = g > (KLEN - 1) ? (KLEN - 1) : g;  // clamped rows feed only masked cells
            rpf[t] = *(const int4*)(Rhp + (size_t)gc * DH + scol);
        }
    }

    for (int c = c_lo; c < c_hi; ++c) {
        const int j0 = c << 6;
        const int wb = 960 - i0 + j0;      // window base (global R row of wr=0)

        // ds-write the prefetched K chunk (Kt/Rt readers done at prior barrier)
        *(int4*)&Kt[(size_t)srow * 72 + scol]        = kpf[0];
        *(int4*)&Kt[(size_t)(srow + 32) * 72 + scol] = kpf[1];
        if (c == c_lo) {
#pragma unroll
            for (int t = 0; t < 4; ++t) {
                int g = wb + srow + t * 32;
                *(int4*)&Rt[(size_t)(g & 127) * 72 + scol] = rpf[t];
            }
        } else {
#pragma unroll
            for (int t = 0; t < 2; ++t) {
                int g = wb + 64 + srow + t * 32;
                *(int4*)&Rt[(size_t)(g & 127) * 72 + scol] = rpf[t];
            }
        }

        // issue THIS chunk's V^T PV-fragments -> registers (consumed after
        // softmax: latency hidden under BD/AC/softmax)
        short8 vpf[2][4];
#pragma unroll
        for (int kt = 0; kt < 2; ++kt)
#pragma unroll
            for (int nt = 0; nt < 4; ++nt)
                vpf[kt][nt] = *(const short8*)(
                    Vh + (size_t)(nt * 16 + lr) * KLEN + j0 + kt * 32 + quad * 8);

        // issue NEXT chunk's K + new R ring rows -> registers
        if (c + 1 < c_hi) {
            const int j1 = j0 + 64;
            kpf[0] = *(const int4*)(Kh + (size_t)(j1 + srow) * DH + scol);
            kpf[1] = *(const int4*)(Kh + (size_t)(j1 + srow + 32) * DH + scol);
            const int wb1 = wb + 64;
#pragma unroll
            for (int t = 0; t < 2; ++t) {
                int g = wb1 + 64 + srow + t * 32;
                int gc = g > (KLEN - 1) ? (KLEN - 1) : g;
                rpf[t] = *(const int4*)(Rhp + (size_t)gc * DH + scol);
            }
        }

        __syncthreads();   // B: staging visible

        // BD: 5 window col-tiles -> Bw (f32)
#pragma unroll
        for (int ctl = 0; ctl < 5; ++ctl) {
            const int wr = (stw + ctl) * 16 + lr;
            const int ring = (wb + wr) & 127;
            f32x4 z = (f32x4){0.f, 0.f, 0.f, 0.f};
#pragma unroll
            for (int kt = 0; kt < 2; ++kt) {
                short8 rb2 = *(const short8*)&Rt[ring * 72 + kt * 32 + quad * 8];
                z = __builtin_amdgcn_mfma_f32_16x16x32_bf16(qbf[kt], rb2, z, 0, 0, 0);
            }
#pragma unroll
            for (int rg = 0; rg < 4; ++rg)
                Bw[w][quad * 4 + rg][ctl * 16 + lr] = z[rg];
        }
        // AC: add at shifted col jj + 15 - row
#pragma unroll
        for (int ct = 0; ct < 4; ++ct) {
            f32x4 z = (f32x4){0.f, 0.f, 0.f, 0.f};
#pragma unroll
            for (int kt = 0; kt < 2; ++kt) {
                short8 kb2 = *(const short8*)&Kt[(ct * 16 + lr) * 72 + kt * 32 + quad * 8];
                z = __builtin_amdgcn_mfma_f32_16x16x32_bf16(qaf[kt], kb2, z, 0, 0, 0);
            }
#pragma unroll
            for (int rg = 0; rg < 4; ++rg) {
                const int rrow = quad * 4 + rg;
                Bw[w][rrow][ct * 16 + lr + 15 - rrow] += z[rg];
            }
        }

        // online softmax; lane's 16 probs == its PV A-fragment
        const int lim = i0 + w * 16 + lr + 1024 - j0;
        float pv[16];
        float mx = -3.4e38f;
#pragma unroll
        for (int kt = 0; kt < 2; ++kt)
#pragma unroll
            for (int t = 0; t < 8; ++t) {
                const int jj = kt * 32 + quad * 8 + t;
                float sv = Bw[w][lr][jj + 15 - lr] * SC;
                sv = (jj > lim) ? -3.4e38f : sv;
                pv[kt * 8 + t] = sv;
                mx = fmaxf(mx, sv);
            }
        mx = fmaxf(mx, __shfl_xor(mx, 16, 64));
        mx = fmaxf(mx, __shfl_xor(mx, 32, 64));
        const float m_new = fmaxf(m_run, mx);
        float ps = 0.f;
        short8 pf[2];
#pragma unroll
        for (int kt = 0; kt < 2; ++kt)
#pragma unroll
            for (int t = 0; t < 8; ++t) {
                const float e = exp2f(pv[kt * 8 + t] - m_new);
                ps += e;
                pf[kt][t] = (short)f2bf(e);
            }
        ps += __shfl_xor(ps, 16, 64);
        ps += __shfl_xor(ps, 32, 64);
        const float alpha = exp2f(m_run - m_new);
        m_run = m_new;
        l_run = l_run * alpha + ps;

        __syncthreads();   // C: all Bw/Kt/Rt reads done -> next writes safe

        float ar[4];
#pragma unroll
        for (int rg = 0; rg < 4; ++rg)
            ar[rg] = __shfl(alpha, quad * 4 + rg, 64);
#pragma unroll
        for (int nt = 0; nt < 4; ++nt) {
            O[nt][0] *= ar[0]; O[nt][1] *= ar[1];
            O[nt][2] *= ar[2]; O[nt][3] *= ar[3];
        }
#pragma unroll
        for (int kt = 0; kt < 2; ++kt)
#pragma unroll
            for (int nt = 0; nt < 4; ++nt)
                O[nt] = __builtin_amdgcn_mfma_f32_16x16x32_bf16(pf[kt], vpf[kt][nt], O[nt], 0, 0, 0);
    }

    if (quad == 0) {
        const size_t mi = ((size_t)s * 32 + bh) * QLEN + i0 + w * 16 + lr;
        Mp[mi] = m_run;
        Lp[mi] = l_run;
    }
    float* Op = s ? Op1 : Op0;
#pragma unroll
    for (int nt = 0; nt < 4; ++nt)
#pragma unroll
        for (int rg = 0; rg < 4; ++rg) {
            const int i = i0 + w * 16 + quad * 4 + rg;
            Op[((size_t)i * BSZc + b) * DM + h * DH + nt * 16 + lr] = O[nt][rg];
        }
}

// ---------------------------------------------------------------------------
// merge split-K partials -> bf16 attn_vec
// ---------------------------------------------------------------------------
__global__ __launch_bounds__(256)
void attn_merge(const float* __restrict__ O0, const float* __restrict__ O1,
                const float* __restrict__ Mp, const float* __restrict__ Lp,
                ushort_t* __restrict__ AV)
{
    const int row = blockIdx.x;           // i*BSZ + b
    const int tid = threadIdx.x;
    const int i = row >> 1, b = row & 1;
    const int h = tid >> 4;
    const int bh = b * NH + h;
    const size_t mi = (size_t)bh * QLEN + i;
    const float m1 = Mp[mi],             l1 = Lp[mi];
    const float m2 = Mp[32 * QLEN + mi], l2 = Lp[32 * QLEN + mi];
    const float M = fmaxf(m1, m2);
    const float a1 = exp2f(m1 - M), a2 = exp2f(m2 - M);
    const float rl = 1.f / (l1 * a1 + l2 * a2);
    const float f1 = a1 * rl, f2 = a2 * rl;
    const float4 o1 = ((const float4*)(O0 + (size_t)row * DM))[tid];
    const float4 o2 = ((const float4*)(O1 + (size_t)row * DM))[tid];
    ushort_t* p = AV + (size_t)row * DM + tid * 4;
    p[0] = f2bf(o1.x * f1 + o2.x * f2);
    p[1] = f2bf(o1.y * f1 + o2.y * f2);
    p[2] = f2bf(o1.z * f1 + o2.z * f2);
    p[3] = f2bf(o1.w * f1 + o2.w * f2);
}

// ---------------------------------------------------------------------------
// out = LayerNorm(X + Y0 [+ Y1]); optional bf16 secondary output
// ---------------------------------------------------------------------------
__global__ __launch_bounds__(256)
void add_ln(const float* __restrict__ X, const float* __restrict__ Y0,
            const float* __restrict__ Y1,
            const float* __restrict__ gg, const float* __restrict__ bb,
            float* __restrict__ out, ushort_t* __restrict__ outb)
{
    const int row  = blockIdx.x;
    const int tid  = threadIdx.x;
    const int lane = tid & 63;
    const int w    = tid >> 6;
    __shared__ float ssum[4], ssq[4];

    const float4 xv = ((const float4*)(X + (size_t)row * DM))[tid];
    const float4 yv = ((const float4*)(Y0 + (size_t)row * DM))[tid];
    float v0 = xv.x + yv.x, v1 = xv.y + yv.y;
    float v2 = xv.z + yv.z, v3 = xv.w + yv.w;
    if (Y1) {
        const float4 zv = ((const float4*)(Y1 + (size_t)row * DM))[tid];
        v0 += zv.x; v1 += zv.y; v2 += zv.z; v3 += zv.w;
    }
    float s = v0 + v1 + v2 + v3;
    float q = v0 * v0 + v1 * v1 + v2 * v2 + v3 * v3;
#pragma unroll
    for (int off = 32; off > 0; off >>= 1) {
        s += __shfl_xor(s, off, 64);
        q += __shfl_xor(q, off, 64);
    }
    if (lane == 0) { ssum[w] = s; ssq[w] = q; }
    __syncthreads();
    s = ssum[0] + ssum[1] + ssum[2] + ssum[3];
    q = ssq[0] + ssq[1] + ssq[2] + ssq[3];
    const float mean = s * (1.f / DM);
    const float var  = q * (1.f / DM) - mean * mean;
    const float rs   = rsqrtf(var + 1e-5f);
    const float4 g4 = ((const float4*)gg)[tid];
    const float4 b4 = ((const float4*)bb)[tid];
    float4 ov;
    ov.x = (v0 - mean) * rs * g4.x + b4.x;
    ov.y = (v1 - mean) * rs * g4.y + b4.y;
    ov.z = (v2 - mean) * rs * g4.z + b4.z;
    ov.w = (v3 - mean) * rs * g4.w + b4.w;
    ((float4*)(out + (size_t)row * DM))[tid] = ov;
    if (outb) {
        ushort_t* p = outb + (size_t)row * DM + tid * 4;
        p[0] = f2bf(ov.x); p[1] = f2bf(ov.y);
        p[2] = f2bf(ov.z); p[3] = f2bf(ov.w);
    }
}

// ---------------------------------------------------------------------------
extern "C" void kernel_launch(void* const* d_in, const int* in_sizes, int n_in,
                              void* d_out, int out_size, void* d_ws, size_t ws_size,
                              hipStream_t stream)
{
    (void)in_sizes; (void)n_in; (void)out_size; (void)ws_size;
    const float* w      = (const float*)d_in[0];
    const float* r      = (const float*)d_in[1];
    const float* mems   = (const float*)d_in[2];
    // d_in[3] attn_mask: deterministic (j > i + MLEN), applied analytically
    const float* qkv_w  = (const float*)d_in[4];
    const float* rnet_w = (const float*)d_in[5];
    const float* o_w    = (const float*)d_in[6];
    const float* r_r_b  = (const float*)d_in[7];
    const float* r_w_b  = (const float*)d_in[8];
    const float* ln1g   = (const float*)d_in[9];
    const float* ln1b   = (const float*)d_in[10];
    const float* ffw1   = (const float*)d_in[11];
    const float* ffb1   = (const float*)d_in[12];
    const float* ffw2   = (const float*)d_in[13];
    const float* ffb2   = (const float*)d_in[14];
    const float* ln2g   = (const float*)d_in[15];
    const float* ln2b   = (const float*)d_in[16];
    float* out = (float*)d_out;

    char* wsb = (char*)d_ws;
    const size_t MB = 1024 * 1024;
    // ---- workspace layout, live ranges verified against launch order ----
    ushort_t* W1    = (ushort_t*)(wsb + 0 * MB);   // 0-6    dead after qkvr
    ushort_t* W2    = (ushort_t*)(wsb + 6 * MB);   // 6-8    dead after qkvr
    ushort_t* Acat  = (ushort_t*)(wsb + 8 * MB);   // 8-16   dead after qkvr
    ushort_t* Rsrc  = (ushort_t*)(wsb + 16 * MB);  // 16-20  dead after qkvr
    ushort_t* Qac   = (ushort_t*)(wsb + 20 * MB);  // 20-24  dead after attn
    ushort_t* Qbd   = (ushort_t*)(wsb + 24 * MB);  // 24-28  dead after attn
    ushort_t* Kbf   = (ushort_t*)(wsb + 28 * MB);  // 28-36  dead after attn
    ushort_t* Vt    = (ushort_t*)(wsb + 36 * MB);  // 36-44  dead after attn
    ushort_t* Rh    = (ushort_t*)(wsb + 44 * MB);  // 44-48  dead after attn
    float*    Op0   = (float*)(wsb + 48 * MB);     // 48-56  attn -> merge
    float*    Op1   = (float*)(wsb + 56 * MB);     // 56-64  attn -> merge
    float*    Mp    = (float*)(wsb + 4 * MB);      // 4-4.25 (over dead W1)
    float*    Lp    = (float*)(wsb + 4 * MB + 512 * 1024); // 4.5-4.75
    ushort_t* AVec  = (ushort_t*)(wsb + 0 * MB);   // 0-4   merge -> o-proj
    ushort_t* W3    = (ushort_t*)(wsb + 4 * MB);   // 4-6   cast2 -> o-proj (over Mp/Lp dead)
    float*    AOut0 = (float*)(wsb + 8 * MB);      // 8-16  o-proj -> ln1 (over Acat dead)
    float*    AOut1 = (float*)(wsb + 44 * MB);     // 44-52 o-proj -> ln1 (over Rh/Op0-head dead)
    float*    Hbuf  = (float*)(wsb + 16 * MB);     // 16-24 ln1 -> ln2 (over Rsrc/Qac dead)
    ushort_t* Hbf   = (ushort_t*)(wsb + 24 * MB);  // 24-28 ln1 -> ff1 (over Qbd dead)
    ushort_t* W4    = (ushort_t*)(wsb + 28 * MB);  // 28-36 cast2 -> ff1 (over Kbf dead)
    ushort_t* FFbf  = (ushort_t*)(wsb + 36 * MB);  // 36-52 ff1 -> ff2 (over Vt/AOut1 dead)
    ushort_t* W5    = (ushort_t*)(wsb + 52 * MB);  // 52-60 cast2 -> ff2 (over Op0-tail/Op1-head dead)
    float*    Core0 = (float*)(wsb + 0 * MB);      // 0-8   ff2 -> ln2 (AVec/W3 dead)
    float*    Core1 = (float*)(wsb + 8 * MB);      // 8-16  ff2 -> ln2 (AOut0 dead)
    // peak 64 MB

    dim3 blk(256);

    // casts for phase 1
    cast_phase1<<<dim3(5120), blk, 0, stream>>>(qkv_w, rnet_w, mems, w, r,
                                                W1, W2, Acat, Rsrc);

    // 1+2. fused QKV + r_net projections
    gemm_qkvr<<<dim3(896), blk, 0, stream>>>(
        Acat, W1, Rsrc, W2, Qac, Qbd, Kbf, Vt, Rh, r_w_b, r_r_b);

    // 3. MFMA flash attention, split-K x2 (contiguous halves) -> partials
    attn_mfma<<<dim3(16, 2, 32), blk, 0, stream>>>(
        Qac, Qbd, Kbf, Vt, Rh, Op0, Op1, Mp, Lp);

    // 3b. merge partials -> bf16 attn_vec
    attn_merge<<<dim3(2048), blk, 0, stream>>>(Op0, Op1, Mp, Lp, AVec);

    // casts for phase 2
    cast_phase2<<<dim3(4608), blk, 0, stream>>>(o_w, ffw1, ffw2, W3, W4, W5);

    // 4. output projection, split-K x2 (f32 partials)
    gemm_mfma<0, 0, 64, 2><<<dim3(16, 16, 2), blk, 0, stream>>>(
        AVec, W3, nullptr, AOut0, AOut1, 2048, 1024, 512, 1024, 1024);

    // 5. h = LN(w + AOut0 + AOut1)  (f32 + bf16 copies)
    add_ln<<<dim3(2 * QLEN), blk, 0, stream>>>(w, AOut0, AOut1, ln1g, ln1b, Hbuf, Hbf);

    // 6. FF1: relu(h @ ff_w1^T + b1) -> bf16
    gemm_mfma<3, 1, 128, 1><<<dim3(16, 32), blk, 0, stream>>>(
        Hbf, W4, ffb1, FFbf, nullptr, 2048, 4096, 1024, 1024, 1024);

    // 7. FF2, split-K x2 -> f32 partials
    gemm_mfma<0, 0, 64, 2><<<dim3(16, 16, 2), blk, 0, stream>>>(
        FFbf, W5, ffb2, Core0, Core1, 2048, 1024, 2048, 4096, 4096);

    // 8. out = LN(h + Core0 + Core1)
    add_ln<<<dim3(2 * QLEN), blk, 0, stream>>>(Hbuf, Core0, Core1, ln2g, ln2b, out, nullptr);
}

// Round 2
// 424.866 us; speedup vs baseline: 1.0658x; 1.0658x over previous
//
#include <hip/hip_runtime.h>
#include <math.h>

#define QLEN 1024
#define MLEN 1024
#define KLEN 2048
#define BSZc 2
#define NH 16
#define DH 64
#define DM 1024
#define DI 4096

typedef unsigned short ushort_t;
typedef __attribute__((ext_vector_type(8))) short short8;
typedef __attribute__((ext_vector_type(4))) float f32x4;

__device__ __forceinline__ ushort_t f2bf(float x) {
    unsigned int u = __float_as_uint(x);
    unsigned int r = (u + 0x7FFFu + ((u >> 16) & 1u)) >> 16;
    return (ushort_t)r;
}

__device__ __forceinline__ void gload_lds16(const ushort_t* g, ushort_t* l) {
    __builtin_amdgcn_global_load_lds(
        (const __attribute__((address_space(1))) unsigned int*)g,
        (__attribute__((address_space(3))) unsigned int*)l,
        16, 0, 0);
}

// ---------------------------------------------------------------------------
// segmented f32 -> bf16 casts (one launch per phase)
// ---------------------------------------------------------------------------
__device__ __forceinline__ void cast8(const float* s, ushort_t* d, int g) {
    const float4 a = *(const float4*)(s + g * 8);
    const float4 b = *(const float4*)(s + g * 8 + 4);
    short8 o;
    o[0] = (short)f2bf(a.x); o[1] = (short)f2bf(a.y);
    o[2] = (short)f2bf(a.z); o[3] = (short)f2bf(a.w);
    o[4] = (short)f2bf(b.x); o[5] = (short)f2bf(b.y);
    o[6] = (short)f2bf(b.z); o[7] = (short)f2bf(b.w);
    *(short8*)(d + g * 8) = o;
}

__global__ __launch_bounds__(256)
void cast_phase1(const float* __restrict__ qkv_w, const float* __restrict__ rnet_w,
                 const float* __restrict__ mems, const float* __restrict__ w,
                 const float* __restrict__ r,
                 ushort_t* __restrict__ W1, ushort_t* __restrict__ W2,
                 ushort_t* __restrict__ Acat, ushort_t* __restrict__ Rsrc)
{
    int g = blockIdx.x * 256 + threadIdx.x;
    if (g < 393216)            { cast8(qkv_w,  W1,              g); }
    else if (g < 524288)       { cast8(rnet_w, W2,              g - 393216); }
    else if (g < 786432)       { cast8(mems,   Acat,            g - 524288); }
    else if (g < 1048576)      { cast8(w,      Acat + 2097152,  g - 786432); }
    else if (g < 1310720)      { cast8(r,      Rsrc,            g - 1048576); }
}

__global__ __launch_bounds__(256)
void cast_phase2(const float* __restrict__ o_w, const float* __restrict__ ffw1,
                 const float* __restrict__ ffw2,
                 ushort_t* __restrict__ W3, ushort_t* __restrict__ W4,
                 ushort_t* __restrict__ W5)
{
    int g = blockIdx.x * 256 + threadIdx.x;
    if (g < 131072)            { cast8(o_w,  W3, g); }
    else if (g < 655360)       { cast8(ffw1, W4, g - 131072); }
    else if (g < 1179648)      { cast8(ffw2, W5, g - 655360); }
}

// ---------------------------------------------------------------------------
// bf16 MFMA GEMM: C = A @ B^T. 128 x BN tile, BK=64 (two BK=32 buffer pairs).
// SPLIT>1: blockIdx.z selects K-slice; partial f32 out; bias only on z==0.
// EMODE 0: f32 out (+bias). EMODE 3: bf16 out (+bias, +relu if ACT).
// ---------------------------------------------------------------------------
template<int EMODE, int ACT, int BN, int SPLIT>
__global__ __launch_bounds__(256)
void gemm_mfma(const ushort_t* __restrict__ A, const ushort_t* __restrict__ B,
               const float* __restrict__ bias,
               void* __restrict__ O0v, void* __restrict__ O1v,
               int M, int N, int Ks, int lda, int ldb)
{
    constexpr int JT = BN / 32;
    __shared__ ushort_t At0[128 * 32];
    __shared__ ushort_t At1[128 * 32];
    __shared__ ushort_t Bt0[BN * 32];
    __shared__ ushort_t Bt1[BN * 32];

    const int tid  = threadIdx.x;
    const int lane = tid & 63;
    const int w    = tid >> 6;
    const int lr   = lane & 15;
    const int quad = lane >> 4;
    const int m0   = blockIdx.x * 128;
    const int n0   = blockIdx.y * BN;
    const int z    = (SPLIT > 1) ? (int)blockIdx.z : 0;
    const int kbase = z * Ks;
    const int wm0  = (w >> 1) * 64;
    const int wn0  = (w & 1) * (BN / 2);

    f32x4 acc[4][JT];
#pragma unroll
    for (int it = 0; it < 4; ++it)
#pragma unroll
        for (int jt = 0; jt < JT; ++jt) acc[it][jt] = (f32x4){0.f, 0.f, 0.f, 0.f};

    const int srow = lane >> 2;
    const int scol = (lane & 3) << 3;
    const ushort_t* Ag = A + (size_t)(m0 + w * 32 + srow) * lda + kbase + scol;
    ushort_t* a00 = At0 + (w * 32) * 32;
    ushort_t* a01 = At0 + (w * 32 + 16) * 32;
    ushort_t* a10 = At1 + (w * 32) * 32;
    ushort_t* a11 = At1 + (w * 32 + 16) * 32;
    const ushort_t* Bg;
    ushort_t *b00, *b01 = nullptr, *b10, *b11 = nullptr;
    if (BN == 128) {
        Bg  = B + (size_t)(n0 + w * 32 + srow) * ldb + kbase + scol;
        b00 = Bt0 + (w * 32) * 32;
        b01 = Bt0 + (w * 32 + 16) * 32;
        b10 = Bt1 + (w * 32) * 32;
        b11 = Bt1 + (w * 32 + 16) * 32;
    } else {
        Bg  = B + (size_t)(n0 + w * 16 + srow) * ldb + kbase + scol;
        b00 = Bt0 + (w * 16) * 32;
        b10 = Bt1 + (w * 16) * 32;
    }

    const ushort_t* Ato0 = At0 + (wm0 + lr) * 32 + quad * 8;
    const ushort_t* Ato1 = At1 + (wm0 + lr) * 32 + quad * 8;
    const ushort_t* Bto0 = Bt0 + (wn0 + lr) * 32 + quad * 8;
    const ushort_t* Bto1 = Bt1 + (wn0 + lr) * 32 + quad * 8;

    for (int k0 = 0; k0 < Ks; k0 += 64) {
        __syncthreads();
        gload_lds16(Ag + k0, a00);
        gload_lds16(Ag + (size_t)16 * lda + k0, a01);
        gload_lds16(Ag + k0 + 32, a10);
        gload_lds16(Ag + (size_t)16 * lda + k0 + 32, a11);
        if (BN == 128) {
            gload_lds16(Bg + k0, b00);
            gload_lds16(Bg + (size_t)16 * ldb + k0, b01);
            gload_lds16(Bg + k0 + 32, b10);
            gload_lds16(Bg + (size_t)16 * ldb + k0 + 32, b11);
        } else {
            gload_lds16(Bg + k0, b00);
            gload_lds16(Bg + k0 + 32, b10);
        }
        __syncthreads();

        short8 af[4], bf[JT];
#pragma unroll
        for (int it = 0; it < 4; ++it)
            af[it] = *(const short8*)(Ato0 + it * 16 * 32);
#pragma unroll
        for (int jt = 0; jt < JT; ++jt)
            bf[jt] = *(const short8*)(Bto0 + jt * 16 * 32);
#pragma unroll
        for (int it = 0; it < 4; ++it)
#pragma unroll
            for (int jt = 0; jt < JT; ++jt)
                acc[it][jt] = __builtin_amdgcn_mfma_f32_16x16x32_bf16(
                    af[it], bf[jt], acc[it][jt], 0, 0, 0);
#pragma unroll
        for (int it = 0; it < 4; ++it)
            af[it] = *(const short8*)(Ato1 + it * 16 * 32);
#pragma unroll
        for (int jt = 0; jt < JT; ++jt)
            bf[jt] = *(const short8*)(Bto1 + jt * 16 * 32);
#pragma unroll
        for (int it = 0; it < 4; ++it)
#pragma unroll
            for (int jt = 0; jt < JT; ++jt)
                acc[it][jt] = __builtin_amdgcn_mfma_f32_16x16x32_bf16(
                    af[it], bf[jt], acc[it][jt], 0, 0, 0);
    }

#pragma unroll
    for (int it = 0; it < 4; ++it)
#pragma unroll
        for (int jt = 0; jt < JT; ++jt)
#pragma unroll
            for (int rg = 0; rg < 4; ++rg) {
                const int m = m0 + wm0 + it * 16 + quad * 4 + rg;
                const int n = n0 + wn0 + jt * 16 + lr;
                float v = acc[it][jt][rg];
                if (EMODE == 0) {
                    float* dst = (float*)(z ? O1v : O0v);
                    if (bias && z == 0) v += bias[n];
                    dst[(size_t)m * N + n] = v;
                } else {
                    v += bias[n];
                    if (ACT == 1) v = fmaxf(v, 0.f);
                    ((ushort_t*)O0v)[(size_t)m * N + n] = f2bf(v);
                }
            }
}

// ---------------------------------------------------------------------------
// Fused QKV + r_net GEMM (BK=32 — known good).
// ---------------------------------------------------------------------------
__global__ __launch_bounds__(256)
void gemm_qkvr(const ushort_t* __restrict__ Acat, const ushort_t* __restrict__ W1,
               const ushort_t* __restrict__ Rsrc, const ushort_t* __restrict__ W2,
               ushort_t* __restrict__ Qac, ushort_t* __restrict__ Qbd,
               ushort_t* __restrict__ Kbf, ushort_t* __restrict__ Vtb,
               ushort_t* __restrict__ Rh,
               const float* __restrict__ rwb, const float* __restrict__ rrb)
{
    __shared__ ushort_t At[128 * 32];
    __shared__ ushort_t Bt[128 * 32];

    const int bid  = blockIdx.x;
    const bool isr = bid >= 768;
    const ushort_t* A; const ushort_t* B; int m0, n0;
    if (!isr) { A = Acat; B = W1; m0 = (bid & 31) * 128; n0 = (bid >> 5) * 128; }
    else { int t = bid - 768; A = Rsrc; B = W2; m0 = (t & 15) * 128; n0 = (t >> 4) * 128; }
    const int K = 1024;

    const int tid  = threadIdx.x;
    const int lane = tid & 63;
    const int w    = tid >> 6;
    const int lr   = lane & 15;
    const int quad = lane >> 4;
    const int wm0  = (w >> 1) * 64;
    const int wn0  = (w & 1) * 64;

    f32x4 acc[4][4];
#pragma unroll
    for (int it = 0; it < 4; ++it)
#pragma unroll
        for (int jt = 0; jt < 4; ++jt) acc[it][jt] = (f32x4){0.f, 0.f, 0.f, 0.f};

    const int srow = lane >> 2;
    const int scol = (lane & 3) << 3;
    const ushort_t* Ag = A + (size_t)(m0 + w * 32 + srow) * K + scol;
    const ushort_t* Bg = B + (size_t)(n0 + w * 32 + srow) * K + scol;
    ushort_t* lA0 = At + (w * 32) * 32;
    ushort_t* lA1 = At + (w * 32 + 16) * 32;
    ushort_t* lB0 = Bt + (w * 32) * 32;
    ushort_t* lB1 = Bt + (w * 32 + 16) * 32;

    const ushort_t* Ato = At + (wm0 + lr) * 32 + quad * 8;
    const ushort_t* Bto = Bt + (wn0 + lr) * 32 + quad * 8;

    for (int k0 = 0; k0 < K; k0 += 32) {
        __syncthreads();
        gload_lds16(Ag + k0, lA0);
        gload_lds16(Ag + (size_t)16 * K + k0, lA1);
        gload_lds16(Bg + k0, lB0);
        gload_lds16(Bg + (size_t)16 * K + k0, lB1);
        __syncthreads();

        short8 af[4], bf[4];
#pragma unroll
        for (int it = 0; it < 4; ++it)
            af[it] = *(const short8*)(Ato + it * 16 * 32);
#pragma unroll
        for (int jt = 0; jt < 4; ++jt)
            bf[jt] = *(const short8*)(Bto + jt * 16 * 32);
#pragma unroll
        for (int it = 0; it < 4; ++it)
#pragma unroll
            for (int jt = 0; jt < 4; ++jt)
                acc[it][jt] = __builtin_amdgcn_mfma_f32_16x16x32_bf16(
                    af[it], bf[jt], acc[it][jt], 0, 0, 0);
    }

#pragma unroll
    for (int it = 0; it < 4; ++it)
#pragma unroll
        for (int jt = 0; jt < 4; ++jt)
#pragma unroll
            for (int rg = 0; rg < 4; ++rg) {
                const int m = m0 + wm0 + it * 16 + quad * 4 + rg;
                const int n = n0 + wn0 + jt * 16 + lr;
                const float v = acc[it][jt][rg];
                if (!isr) {
                    const int j = m >> 1, b = m & 1;
                    const int part = n >> 10, hh = (n >> 6) & 15, d = n & 63;
                    if (part == 0) {
                        if (j >= MLEN) {
                            const int qi = j - MLEN;
                            const size_t qidx = (((size_t)(b * NH + hh)) * QLEN + qi) * DH + d;
                            Qac[qidx] = f2bf(v + rwb[hh * DH + d]);
                            Qbd[qidx] = f2bf(v + rrb[hh * DH + d]);
                        }
                    } else if (part == 1) {
                        Kbf[(((size_t)(b * NH + hh)) * KLEN + j) * DH + d] = f2bf(v);
                    } else {
                        Vtb[(((size_t)(b * NH + hh)) * DH + d) * KLEN + j] = f2bf(v);
                    }
                } else {
                    const int hh = n >> 6, d = n & 63;
                    Rh[(((size_t)hh) * KLEN + m) * DH + d] = f2bf(v);
                }
            }
}

// ---------------------------------------------------------------------------
// MFMA flash attention with TransformerXL rel-shift, split-K x2 (contiguous
// halves so the R window slides 64/chunk -> ring buffer).
//
// Round-2 (surgical version of the T14 idea; round-1's combined restructure
// spilled ~64 B/thread/chunk to scratch -> 137 MB of HBM writes):
//  * K/R staging: round-0 direct int4 global->reg->ds copies at chunk top
//    (NO chunk-ahead register prefetch — that was the spill source).
//  * V^T PV-fragments: REGISTER-prefetched (32 VGPR), issued right after
//    barrier B so their latency hides under BD/AC/softmax; consumed after
//    barrier C. No V LDS staging, no Bw overlay, barrier D eliminated
//    (3 -> 2 barriers/chunk).
//  LDS = Kt(9216) + Rt ring(18432) + Bw f32(21504) = 49152 B -> 3 blocks/CU.
// ---------------------------------------------------------------------------
__global__ __launch_bounds__(256, 3)
void attn_mfma(const ushort_t* __restrict__ Qac, const ushort_t* __restrict__ Qbd,
               const ushort_t* __restrict__ Kb, const ushort_t* __restrict__ Vt,
               const ushort_t* __restrict__ Rb,
               float* __restrict__ Op0, float* __restrict__ Op1,
               float* __restrict__ Mp, float* __restrict__ Lp)
{
    __shared__ __align__(16) ushort_t Kt[64 * 72];     //  9216 B
    __shared__ __align__(16) ushort_t Rt[128 * 72];    // 18432 B, ring
    __shared__ __align__(16) float    Bw[4][16][84];   // 21504 B

    const int tid  = threadIdx.x;
    const int lane = tid & 63;
    const int w    = tid >> 6;
    const int lr   = lane & 15;
    const int quad = lane >> 4;
    const int qt   = blockIdx.x;
    const int s    = blockIdx.y;
    const int bh   = blockIdx.z;
    const int i0   = qt << 6;
    const int h    = bh & 15;
    const int b    = bh >> 4;

    short8 qaf[2], qbf[2];
    {
        const size_t rowoff = ((size_t)bh * QLEN + i0 + w * 16 + lr) * DH;
#pragma unroll
        for (int kt = 0; kt < 2; ++kt) {
            qaf[kt] = *(const short8*)(Qac + rowoff + kt * 32 + quad * 8);
            qbf[kt] = *(const short8*)(Qbd + rowoff + kt * 32 + quad * 8);
        }
    }

    f32x4 O[4];
#pragma unroll
    for (int nt = 0; nt < 4; ++nt) O[nt] = (f32x4){0.f, 0.f, 0.f, 0.f};
    float m_run = -3.4e38f, l_run = 0.f;

    const int nc   = qt + 17;
    const int half = (nc + 1) >> 1;
    const int c_lo = s ? half : 0;
    const int c_hi = s ? nc : half;
    const int stw  = 3 - w;
    const float SC = 0.125f * 1.44269504f;   // scale * log2(e)
    const ushort_t* Kh  = Kb + (size_t)bh * KLEN * DH;
    const ushort_t* Vh  = Vt + (size_t)bh * DH * KLEN;
    const ushort_t* Rhp = Rb + (size_t)h * KLEN * DH;

    for (int c = c_lo; c < c_hi; ++c) {
        const int j0 = c << 6;
        const int wb = 960 - i0 + j0;      // window base (global R row of wr=0)

        // stage K chunk (Kt free: its readers finished before prior barrier C)
#pragma unroll
        for (int t = 0; t < 2; ++t) {
            int f = tid + (t << 8);
            int row = f >> 3, c8 = (f & 7) << 3;
            *(int4*)&Kt[row * 72 + c8] = *(const int4*)(Kh + (size_t)(j0 + row) * DH + c8);
        }
        // stage R (ring): first chunk 128 rows, later 64 new rows
        if (c == c_lo) {
#pragma unroll
            for (int t = 0; t < 4; ++t) {
                int f = tid + (t << 8);
                int rl2 = f >> 3, c8 = (f & 7) << 3;
                int g = wb + rl2;
                int gc = g > (KLEN - 1) ? (KLEN - 1) : g;  // clamped rows feed only masked cells
                *(int4*)&Rt[((g) & 127) * 72 + c8] = *(const int4*)(Rhp + (size_t)gc * DH + c8);
            }
        } else {
#pragma unroll
            for (int t = 0; t < 2; ++t) {
                int f = tid + (t << 8);
                int rl2 = (f >> 3) + 64, c8 = (f & 7) << 3;
                int g = wb + rl2;
                int gc = g > (KLEN - 1) ? (KLEN - 1) : g;
                *(int4*)&Rt[((g) & 127) * 72 + c8] = *(const int4*)(Rhp + (size_t)gc * DH + c8);
            }
        }
        __syncthreads();   // B: staging visible

        // issue THIS chunk's V^T PV-fragments -> registers; latency hides
        // under BD/AC/softmax (issued after the barrier so the barrier's
        // vmcnt(0) drain doesn't serialize them)
        short8 vpf[2][4];
#pragma unroll
        for (int kt = 0; kt < 2; ++kt)
#pragma unroll
            for (int nt = 0; nt < 4; ++nt)
                vpf[kt][nt] = *(const short8*)(
                    Vh + (size_t)(nt * 16 + lr) * KLEN + j0 + kt * 32 + quad * 8);

        // BD: 5 window col-tiles -> Bw (f32)
#pragma unroll
        for (int ctl = 0; ctl < 5; ++ctl) {
            const int wr = (stw + ctl) * 16 + lr;
            const int ring = (wb + wr) & 127;
            f32x4 z = (f32x4){0.f, 0.f, 0.f, 0.f};
#pragma unroll
            for (int kt = 0; kt < 2; ++kt) {
                short8 rb2 = *(const short8*)&Rt[ring * 72 + kt * 32 + quad * 8];
                z = __builtin_amdgcn_mfma_f32_16x16x32_bf16(qbf[kt], rb2, z, 0, 0, 0);
            }
#pragma unroll
            for (int rg = 0; rg < 4; ++rg)
                Bw[w][quad * 4 + rg][ctl * 16 + lr] = z[rg];
        }
        // AC: add at shifted col jj + 15 - row
#pragma unroll
        for (int ct = 0; ct < 4; ++ct) {
            f32x4 z = (f32x4){0.f, 0.f, 0.f, 0.f};
#pragma unroll
            for (int kt = 0; kt < 2; ++kt) {
                short8 kb2 = *(const short8*)&Kt[(ct * 16 + lr) * 72 + kt * 32 + quad * 8];
                z = __builtin_amdgcn_mfma_f32_16x16x32_bf16(qaf[kt], kb2, z, 0, 0, 0);
            }
#pragma unroll
            for (int rg = 0; rg < 4; ++rg) {
                const int rrow = quad * 4 + rg;
                Bw[w][rrow][ct * 16 + lr + 15 - rrow] += z[rg];
            }
        }

        // online softmax; lane's 16 probs == its PV A-fragment
        const int lim = i0 + w * 16 + lr + 1024 - j0;
        float pv[16];
        float mx = -3.4e38f;
#pragma unroll
        for (int kt = 0; kt < 2; ++kt)
#pragma unroll
            for (int t = 0; t < 8; ++t) {
                const int jj = kt * 32 + quad * 8 + t;
                float sv = Bw[w][lr][jj + 15 - lr] * SC;
                sv = (jj > lim) ? -3.4e38f : sv;
                pv[kt * 8 + t] = sv;
                mx = fmaxf(mx, sv);
            }
        mx = fmaxf(mx, __shfl_xor(mx, 16, 64));
        mx = fmaxf(mx, __shfl_xor(mx, 32, 64));
        const float m_new = fmaxf(m_run, mx);
        float ps = 0.f;
        short8 pf[2];
#pragma unroll
        for (int kt = 0; kt < 2; ++kt)
#pragma unroll
            for (int t = 0; t < 8; ++t) {
                const float e = exp2f(pv[kt * 8 + t] - m_new);
                ps += e;
                pf[kt][t] = (short)f2bf(e);
            }
        ps += __shfl_xor(ps, 16, 64);
        ps += __shfl_xor(ps, 32, 64);
        const float alpha = exp2f(m_run - m_new);
        m_run = m_new;
        l_run = l_run * alpha + ps;

        __syncthreads();   // C: all Bw/Kt/Rt reads done -> next writes safe

        float ar[4];
#pragma unroll
        for (int rg = 0; rg < 4; ++rg)
            ar[rg] = __shfl(alpha, quad * 4 + rg, 64);
#pragma unroll
        for (int nt = 0; nt < 4; ++nt) {
            O[nt][0] *= ar[0]; O[nt][1] *= ar[1];
            O[nt][2] *= ar[2]; O[nt][3] *= ar[3];
        }
#pragma unroll
        for (int kt = 0; kt < 2; ++kt)
#pragma unroll
            for (int nt = 0; nt < 4; ++nt)
                O[nt] = __builtin_amdgcn_mfma_f32_16x16x32_bf16(pf[kt], vpf[kt][nt], O[nt], 0, 0, 0);
    }

    if (quad == 0) {
        const size_t mi = ((size_t)s * 32 + bh) * QLEN + i0 + w * 16 + lr;
        Mp[mi] = m_run;
        Lp[mi] = l_run;
    }
    float* Op = s ? Op1 : Op0;
#pragma unroll
    for (int nt = 0; nt < 4; ++nt)
#pragma unroll
        for (int rg = 0; rg < 4; ++rg) {
            const int i = i0 + w * 16 + quad * 4 + rg;
            Op[((size_t)i * BSZc + b) * DM + h * DH + nt * 16 + lr] = O[nt][rg];
        }
}

// ---------------------------------------------------------------------------
// merge split-K partials -> bf16 attn_vec
// ---------------------------------------------------------------------------
__global__ __launch_bounds__(256)
void attn_merge(const float* __restrict__ O0, const float* __restrict__ O1,
                const float* __restrict__ Mp, const float* __restrict__ Lp,
                ushort_t* __restrict__ AV)
{
    const int row = blockIdx.x;           // i*BSZ + b
    const int tid = threadIdx.x;
    const int i = row >> 1, b = row & 1;
    const int h = tid >> 4;
    const int bh = b * NH + h;
    const size_t mi = (size_t)bh * QLEN + i;
    const float m1 = Mp[mi],             l1 = Lp[mi];
    const float m2 = Mp[32 * QLEN + mi], l2 = Lp[32 * QLEN + mi];
    const float M = fmaxf(m1, m2);
    const float a1 = exp2f(m1 - M), a2 = exp2f(m2 - M);
    const float rl = 1.f / (l1 * a1 + l2 * a2);
    const float f1 = a1 * rl, f2 = a2 * rl;
    const float4 o1 = ((const float4*)(O0 + (size_t)row * DM))[tid];
    const float4 o2 = ((const float4*)(O1 + (size_t)row * DM))[tid];
    ushort_t* p = AV + (size_t)row * DM + tid * 4;
    p[0] = f2bf(o1.x * f1 + o2.x * f2);
    p[1] = f2bf(o1.y * f1 + o2.y * f2);
    p[2] = f2bf(o1.z * f1 + o2.z * f2);
    p[3] = f2bf(o1.w * f1 + o2.w * f2);
}

// ---------------------------------------------------------------------------
// out = LayerNorm(X + Y0 [+ Y1]); optional bf16 secondary output
// ---------------------------------------------------------------------------
__global__ __launch_bounds__(256)
void add_ln(const float* __restrict__ X, const float* __restrict__ Y0,
            const float* __restrict__ Y1,
            const float* __restrict__ gg, const float* __restrict__ bb,
            float* __restrict__ out, ushort_t* __restrict__ outb)
{
    const int row  = blockIdx.x;
    const int tid  = threadIdx.x;
    const int lane = tid & 63;
    const int w    = tid >> 6;
    __shared__ float ssum[4], ssq[4];

    const float4 xv = ((const float4*)(X + (size_t)row * DM))[tid];
    const float4 yv = ((const float4*)(Y0 + (size_t)row * DM))[tid];
    float v0 = xv.x + yv.x, v1 = xv.y + yv.y;
    float v2 = xv.z + yv.z, v3 = xv.w + yv.w;
    if (Y1) {
        const float4 zv = ((const float4*)(Y1 + (size_t)row * DM))[tid];
        v0 += zv.x; v1 += zv.y; v2 += zv.z; v3 += zv.w;
    }
    float s = v0 + v1 + v2 + v3;
    float q = v0 * v0 + v1 * v1 + v2 * v2 + v3 * v3;
#pragma unroll
    for (int off = 32; off > 0; off >>= 1) {
        s += __shfl_xor(s, off, 64);
        q += __shfl_xor(q, off, 64);
    }
    if (lane == 0) { ssum[w] = s; ssq[w] = q; }
    __syncthreads();
    s = ssum[0] + ssum[1] + ssum[2] + ssum[3];
    q = ssq[0] + ssq[1] + ssq[2] + ssq[3];
    const float mean = s * (1.f / DM);
    const float var  = q * (1.f / DM) - mean * mean;
    const float rs   = rsqrtf(var + 1e-5f);
    const float4 g4 = ((const float4*)gg)[tid];
    const float4 b4 = ((const float4*)bb)[tid];
    float4 ov;
    ov.x = (v0 - mean) * rs * g4.x + b4.x;
    ov.y = (v1 - mean) * rs * g4.y + b4.y;
    ov.z = (v2 - mean) * rs * g4.z + b4.z;
    ov.w = (v3 - mean) * rs * g4.w + b4.w;
    ((float4*)(out + (size_t)row * DM))[tid] = ov;
    if (outb) {
        ushort_t* p = outb + (size_t)row * DM + tid * 4;
        p[0] = f2bf(ov.x); p[1] = f2bf(ov.y);
        p[2] = f2bf(ov.z); p[3] = f2bf(ov.w);
    }
}

// ---------------------------------------------------------------------------
extern "C" void kernel_launch(void* const* d_in, const int* in_sizes, int n_in,
                              void* d_out, int out_size, void* d_ws, size_t ws_size,
                              hipStream_t stream)
{
    (void)in_sizes; (void)n_in; (void)out_size; (void)ws_size;
    const float* w      = (const float*)d_in[0];
    const float* r      = (const float*)d_in[1];
    const float* mems   = (const float*)d_in[2];
    // d_in[3] attn_mask: deterministic (j > i + MLEN), applied analytically
    const float* qkv_w  = (const float*)d_in[4];
    const float* rnet_w = (const float*)d_in[5];
    const float* o_w    = (const float*)d_in[6];
    const float* r_r_b  = (const float*)d_in[7];
    const float* r_w_b  = (const float*)d_in[8];
    const float* ln1g   = (const float*)d_in[9];
    const float* ln1b   = (const float*)d_in[10];
    const float* ffw1   = (const float*)d_in[11];
    const float* ffb1   = (const float*)d_in[12];
    const float* ffw2   = (const float*)d_in[13];
    const float* ffb2   = (const float*)d_in[14];
    const float* ln2g   = (const float*)d_in[15];
    const float* ln2b   = (const float*)d_in[16];
    float* out = (float*)d_out;

    char* wsb = (char*)d_ws;
    const size_t MB = 1024 * 1024;
    // ---- workspace layout, live ranges verified against launch order ----
    ushort_t* W1    = (ushort_t*)(wsb + 0 * MB);   // 0-6    dead after qkvr
    ushort_t* W2    = (ushort_t*)(wsb + 6 * MB);   // 6-8    dead after qkvr
    ushort_t* Acat  = (ushort_t*)(wsb + 8 * MB);   // 8-16   dead after qkvr
    ushort_t* Rsrc  = (ushort_t*)(wsb + 16 * MB);  // 16-20  dead after qkvr
    ushort_t* Qac   = (ushort_t*)(wsb + 20 * MB);  // 20-24  dead after attn
    ushort_t* Qbd   = (ushort_t*)(wsb + 24 * MB);  // 24-28  dead after attn
    ushort_t* Kbf   = (ushort_t*)(wsb + 28 * MB);  // 28-36  dead after attn
    ushort_t* Vt    = (ushort_t*)(wsb + 36 * MB);  // 36-44  dead after attn
    ushort_t* Rh    = (ushort_t*)(wsb + 44 * MB);  // 44-48  dead after attn
    float*    Op0   = (float*)(wsb + 48 * MB);     // 48-56  attn -> merge
    float*    Op1   = (float*)(wsb + 56 * MB);     // 56-64  attn -> merge
    float*    Mp    = (float*)(wsb + 4 * MB);      // 4-4.25 (over dead W1)
    float*    Lp    = (float*)(wsb + 4 * MB + 512 * 1024); // 4.5-4.75
    ushort_t* AVec  = (ushort_t*)(wsb + 0 * MB);   // 0-4   merge -> o-proj
    ushort_t* W3    = (ushort_t*)(wsb + 4 * MB);   // 4-6   cast2 -> o-proj (over Mp/Lp dead)
    float*    AOut0 = (float*)(wsb + 8 * MB);      // 8-16  o-proj -> ln1 (over Acat dead)
    float*    AOut1 = (float*)(wsb + 44 * MB);     // 44-52 o-proj -> ln1 (over Rh/Op0-head dead)
    float*    Hbuf  = (float*)(wsb + 16 * MB);     // 16-24 ln1 -> ln2 (over Rsrc/Qac dead)
    ushort_t* Hbf   = (ushort_t*)(wsb + 24 * MB);  // 24-28 ln1 -> ff1 (over Qbd dead)
    ushort_t* W4    = (ushort_t*)(wsb + 28 * MB);  // 28-36 cast2 -> ff1 (over Kbf dead)
    ushort_t* FFbf  = (ushort_t*)(wsb + 36 * MB);  // 36-52 ff1 -> ff2 (over Vt/AOut1 dead)
    ushort_t* W5    = (ushort_t*)(wsb + 52 * MB);  // 52-60 cast2 -> ff2 (over Op0-tail/Op1-head dead)
    float*    Core0 = (float*)(wsb + 0 * MB);      // 0-8   ff2 -> ln2 (AVec/W3 dead)
    float*    Core1 = (float*)(wsb + 8 * MB);      // 8-16  ff2 -> ln2 (AOut0 dead)
    // peak 64 MB

    dim3 blk(256);

    // casts for phase 1
    cast_phase1<<<dim3(5120), blk, 0, stream>>>(qkv_w, rnet_w, mems, w, r,
                                                W1, W2, Acat, Rsrc);

    // 1+2. fused QKV + r_net projections
    gemm_qkvr<<<dim3(896), blk, 0, stream>>>(
        Acat, W1, Rsrc, W2, Qac, Qbd, Kbf, Vt, Rh, r_w_b, r_r_b);

    // 3. MFMA flash attention, split-K x2 (contiguous halves) -> partials
    attn_mfma<<<dim3(16, 2, 32), blk, 0, stream>>>(
        Qac, Qbd, Kbf, Vt, Rh, Op0, Op1, Mp, Lp);

    // 3b. merge partials -> bf16 attn_vec
    attn_merge<<<dim3(2048), blk, 0, stream>>>(Op0, Op1, Mp, Lp, AVec);

    // casts for phase 2
    cast_phase2<<<dim3(4608), blk, 0, stream>>>(o_w, ffw1, ffw2, W3, W4, W5);

    // 4. output projection, split-K x2 (f32 partials)
    gemm_mfma<0, 0, 64, 2><<<dim3(16, 16, 2), blk, 0, stream>>>(
        AVec, W3, nullptr, AOut0, AOut1, 2048, 1024, 512, 1024, 1024);

    // 5. h = LN(w + AOut0 + AOut1)  (f32 + bf16 copies)
    add_ln<<<dim3(2 * QLEN), blk, 0, stream>>>(w, AOut0, AOut1, ln1g, ln1b, Hbuf, Hbf);

    // 6. FF1: relu(h @ ff_w1^T + b1) -> bf16
    gemm_mfma<3, 1, 128, 1><<<dim3(16, 32), blk, 0, stream>>>(
        Hbf, W4, ffb1, FFbf, nullptr, 2048, 4096, 1024, 1024, 1024);

    // 7. FF2, split-K x2 -> f32 partials
    gemm_mfma<0, 0, 64, 2><<<dim3(16, 16, 2), blk, 0, stream>>>(
        FFbf, W5, ffb2, Core0, Core1, 2048, 1024, 2048, 4096, 4096);

    // 8. out = LN(h + Core0 + Core1)
    add_ln<<<dim3(2 * QLEN), blk, 0, stream>>>(Hbuf, Core0, Core1, ln2g, ln2b, out, nullptr);
}

// Round 4
// 394.048 us; speedup vs baseline: 1.1491x; 1.0782x over previous
//
#include <hip/hip_runtime.h>
#include <math.h>

#define QLEN 1024
#define MLEN 1024
#define KLEN 2048
#define BSZc 2
#define NH 16
#define DH 64
#define DM 1024
#define DI 4096

typedef unsigned short ushort_t;
typedef __attribute__((ext_vector_type(8))) short short8;
typedef __attribute__((ext_vector_type(4))) float f32x4;

__device__ __forceinline__ ushort_t f2bf(float x) {
    unsigned int u = __float_as_uint(x);
    unsigned int r = (u + 0x7FFFu + ((u >> 16) & 1u)) >> 16;
    return (ushort_t)r;
}

__device__ __forceinline__ void gload_lds16(const ushort_t* g, ushort_t* l) {
    __builtin_amdgcn_global_load_lds(
        (const __attribute__((address_space(1))) unsigned int*)g,
        (__attribute__((address_space(3))) unsigned int*)l,
        16, 0, 0);
}

// ---------------------------------------------------------------------------
// segmented f32 -> bf16 casts (one launch per phase)
// ---------------------------------------------------------------------------
__device__ __forceinline__ void cast8(const float* s, ushort_t* d, int g) {
    const float4 a = *(const float4*)(s + g * 8);
    const float4 b = *(const float4*)(s + g * 8 + 4);
    short8 o;
    o[0] = (short)f2bf(a.x); o[1] = (short)f2bf(a.y);
    o[2] = (short)f2bf(a.z); o[3] = (short)f2bf(a.w);
    o[4] = (short)f2bf(b.x); o[5] = (short)f2bf(b.y);
    o[6] = (short)f2bf(b.z); o[7] = (short)f2bf(b.w);
    *(short8*)(d + g * 8) = o;
}

__global__ __launch_bounds__(256)
void cast_phase1(const float* __restrict__ qkv_w, const float* __restrict__ rnet_w,
                 const float* __restrict__ mems, const float* __restrict__ w,
                 const float* __restrict__ r,
                 ushort_t* __restrict__ W1, ushort_t* __restrict__ W2,
                 ushort_t* __restrict__ Acat, ushort_t* __restrict__ Rsrc)
{
    int g = blockIdx.x * 256 + threadIdx.x;
    if (g < 393216)            { cast8(qkv_w,  W1,              g); }
    else if (g < 524288)       { cast8(rnet_w, W2,              g - 393216); }
    else if (g < 786432)       { cast8(mems,   Acat,            g - 524288); }
    else if (g < 1048576)      { cast8(w,      Acat + 2097152,  g - 786432); }
    else if (g < 1310720)      { cast8(r,      Rsrc,            g - 1048576); }
}

__global__ __launch_bounds__(256)
void cast_phase2(const float* __restrict__ o_w, const float* __restrict__ ffw1,
                 const float* __restrict__ ffw2,
                 ushort_t* __restrict__ W3, ushort_t* __restrict__ W4,
                 ushort_t* __restrict__ W5)
{
    int g = blockIdx.x * 256 + threadIdx.x;
    if (g < 131072)            { cast8(o_w,  W3, g); }
    else if (g < 655360)       { cast8(ffw1, W4, g - 131072); }
    else if (g < 1179648)      { cast8(ffw2, W5, g - 655360); }
}

// ---------------------------------------------------------------------------
// bf16 MFMA GEMM: C = A @ B^T. 128 x BN tile, BK=64 (two BK=32 buffer pairs).
// SPLIT>1: blockIdx.z selects K-slice; partial f32 out; bias only on z==0.
// EMODE 0: f32 out (+bias). EMODE 3: bf16 out (+bias, +relu if ACT).
// ---------------------------------------------------------------------------
template<int EMODE, int ACT, int BN, int SPLIT>
__global__ __launch_bounds__(256)
void gemm_mfma(const ushort_t* __restrict__ A, const ushort_t* __restrict__ B,
               const float* __restrict__ bias,
               void* __restrict__ O0v, void* __restrict__ O1v,
               int M, int N, int Ks, int lda, int ldb)
{
    constexpr int JT = BN / 32;
    __shared__ ushort_t At0[128 * 32];
    __shared__ ushort_t At1[128 * 32];
    __shared__ ushort_t Bt0[BN * 32];
    __shared__ ushort_t Bt1[BN * 32];

    const int tid  = threadIdx.x;
    const int lane = tid & 63;
    const int w    = tid >> 6;
    const int lr   = lane & 15;
    const int quad = lane >> 4;
    const int m0   = blockIdx.x * 128;
    const int n0   = blockIdx.y * BN;
    const int z    = (SPLIT > 1) ? (int)blockIdx.z : 0;
    const int kbase = z * Ks;
    const int wm0  = (w >> 1) * 64;
    const int wn0  = (w & 1) * (BN / 2);

    f32x4 acc[4][JT];
#pragma unroll
    for (int it = 0; it < 4; ++it)
#pragma unroll
        for (int jt = 0; jt < JT; ++jt) acc[it][jt] = (f32x4){0.f, 0.f, 0.f, 0.f};

    const int srow = lane >> 2;
    const int scol = (lane & 3) << 3;
    const ushort_t* Ag = A + (size_t)(m0 + w * 32 + srow) * lda + kbase + scol;
    ushort_t* a00 = At0 + (w * 32) * 32;
    ushort_t* a01 = At0 + (w * 32 + 16) * 32;
    ushort_t* a10 = At1 + (w * 32) * 32;
    ushort_t* a11 = At1 + (w * 32 + 16) * 32;
    const ushort_t* Bg;
    ushort_t *b00, *b01 = nullptr, *b10, *b11 = nullptr;
    if (BN == 128) {
        Bg  = B + (size_t)(n0 + w * 32 + srow) * ldb + kbase + scol;
        b00 = Bt0 + (w * 32) * 32;
        b01 = Bt0 + (w * 32 + 16) * 32;
        b10 = Bt1 + (w * 32) * 32;
        b11 = Bt1 + (w * 32 + 16) * 32;
    } else {
        Bg  = B + (size_t)(n0 + w * 16 + srow) * ldb + kbase + scol;
        b00 = Bt0 + (w * 16) * 32;
        b10 = Bt1 + (w * 16) * 32;
    }

    const ushort_t* Ato0 = At0 + (wm0 + lr) * 32 + quad * 8;
    const ushort_t* Ato1 = At1 + (wm0 + lr) * 32 + quad * 8;
    const ushort_t* Bto0 = Bt0 + (wn0 + lr) * 32 + quad * 8;
    const ushort_t* Bto1 = Bt1 + (wn0 + lr) * 32 + quad * 8;

    for (int k0 = 0; k0 < Ks; k0 += 64) {
        __syncthreads();
        gload_lds16(Ag + k0, a00);
        gload_lds16(Ag + (size_t)16 * lda + k0, a01);
        gload_lds16(Ag + k0 + 32, a10);
        gload_lds16(Ag + (size_t)16 * lda + k0 + 32, a11);
        if (BN == 128) {
            gload_lds16(Bg + k0, b00);
            gload_lds16(Bg + (size_t)16 * ldb + k0, b01);
            gload_lds16(Bg + k0 + 32, b10);
            gload_lds16(Bg + (size_t)16 * ldb + k0 + 32, b11);
        } else {
            gload_lds16(Bg + k0, b00);
            gload_lds16(Bg + k0 + 32, b10);
        }
        __syncthreads();

        short8 af[4], bf[JT];
#pragma unroll
        for (int it = 0; it < 4; ++it)
            af[it] = *(const short8*)(Ato0 + it * 16 * 32);
#pragma unroll
        for (int jt = 0; jt < JT; ++jt)
            bf[jt] = *(const short8*)(Bto0 + jt * 16 * 32);
#pragma unroll
        for (int it = 0; it < 4; ++it)
#pragma unroll
            for (int jt = 0; jt < JT; ++jt)
                acc[it][jt] = __builtin_amdgcn_mfma_f32_16x16x32_bf16(
                    af[it], bf[jt], acc[it][jt], 0, 0, 0);
#pragma unroll
        for (int it = 0; it < 4; ++it)
            af[it] = *(const short8*)(Ato1 + it * 16 * 32);
#pragma unroll
        for (int jt = 0; jt < JT; ++jt)
            bf[jt] = *(const short8*)(Bto1 + jt * 16 * 32);
#pragma unroll
        for (int it = 0; it < 4; ++it)
#pragma unroll
            for (int jt = 0; jt < JT; ++jt)
                acc[it][jt] = __builtin_amdgcn_mfma_f32_16x16x32_bf16(
                    af[it], bf[jt], acc[it][jt], 0, 0, 0);
    }

#pragma unroll
    for (int it = 0; it < 4; ++it)
#pragma unroll
        for (int jt = 0; jt < JT; ++jt)
#pragma unroll
            for (int rg = 0; rg < 4; ++rg) {
                const int m = m0 + wm0 + it * 16 + quad * 4 + rg;
                const int n = n0 + wn0 + jt * 16 + lr;
                float v = acc[it][jt][rg];
                if (EMODE == 0) {
                    float* dst = (float*)(z ? O1v : O0v);
                    if (bias && z == 0) v += bias[n];
                    dst[(size_t)m * N + n] = v;
                } else {
                    v += bias[n];
                    if (ACT == 1) v = fmaxf(v, 0.f);
                    ((ushort_t*)O0v)[(size_t)m * N + n] = f2bf(v);
                }
            }
}

// ---------------------------------------------------------------------------
// Fused QKV + r_net GEMM (BK=32 — known good).
// ---------------------------------------------------------------------------
__global__ __launch_bounds__(256)
void gemm_qkvr(const ushort_t* __restrict__ Acat, const ushort_t* __restrict__ W1,
               const ushort_t* __restrict__ Rsrc, const ushort_t* __restrict__ W2,
               ushort_t* __restrict__ Qac, ushort_t* __restrict__ Qbd,
               ushort_t* __restrict__ Kbf, ushort_t* __restrict__ Vtb,
               ushort_t* __restrict__ Rh,
               const float* __restrict__ rwb, const float* __restrict__ rrb)
{
    __shared__ ushort_t At[128 * 32];
    __shared__ ushort_t Bt[128 * 32];

    const int bid  = blockIdx.x;
    const bool isr = bid >= 768;
    const ushort_t* A; const ushort_t* B; int m0, n0;
    if (!isr) { A = Acat; B = W1; m0 = (bid & 31) * 128; n0 = (bid >> 5) * 128; }
    else { int t = bid - 768; A = Rsrc; B = W2; m0 = (t & 15) * 128; n0 = (t >> 4) * 128; }
    const int K = 1024;

    const int tid  = threadIdx.x;
    const int lane = tid & 63;
    const int w    = tid >> 6;
    const int lr   = lane & 15;
    const int quad = lane >> 4;
    const int wm0  = (w >> 1) * 64;
    const int wn0  = (w & 1) * 64;

    f32x4 acc[4][4];
#pragma unroll
    for (int it = 0; it < 4; ++it)
#pragma unroll
        for (int jt = 0; jt < 4; ++jt) acc[it][jt] = (f32x4){0.f, 0.f, 0.f, 0.f};

    const int srow = lane >> 2;
    const int scol = (lane & 3) << 3;
    const ushort_t* Ag = A + (size_t)(m0 + w * 32 + srow) * K + scol;
    const ushort_t* Bg = B + (size_t)(n0 + w * 32 + srow) * K + scol;
    ushort_t* lA0 = At + (w * 32) * 32;
    ushort_t* lA1 = At + (w * 32 + 16) * 32;
    ushort_t* lB0 = Bt + (w * 32) * 32;
    ushort_t* lB1 = Bt + (w * 32 + 16) * 32;

    const ushort_t* Ato = At + (wm0 + lr) * 32 + quad * 8;
    const ushort_t* Bto = Bt + (wn0 + lr) * 32 + quad * 8;

    for (int k0 = 0; k0 < K; k0 += 32) {
        __syncthreads();
        gload_lds16(Ag + k0, lA0);
        gload_lds16(Ag + (size_t)16 * K + k0, lA1);
        gload_lds16(Bg + k0, lB0);
        gload_lds16(Bg + (size_t)16 * K + k0, lB1);
        __syncthreads();

        short8 af[4], bf[4];
#pragma unroll
        for (int it = 0; it < 4; ++it)
            af[it] = *(const short8*)(Ato + it * 16 * 32);
#pragma unroll
        for (int jt = 0; jt < 4; ++jt)
            bf[jt] = *(const short8*)(Bto + jt * 16 * 32);
#pragma unroll
        for (int it = 0; it < 4; ++it)
#pragma unroll
            for (int jt = 0; jt < 4; ++jt)
                acc[it][jt] = __builtin_amdgcn_mfma_f32_16x16x32_bf16(
                    af[it], bf[jt], acc[it][jt], 0, 0, 0);
    }

#pragma unroll
    for (int it = 0; it < 4; ++it)
#pragma unroll
        for (int jt = 0; jt < 4; ++jt)
#pragma unroll
            for (int rg = 0; rg < 4; ++rg) {
                const int m = m0 + wm0 + it * 16 + quad * 4 + rg;
                const int n = n0 + wn0 + jt * 16 + lr;
                const float v = acc[it][jt][rg];
                if (!isr) {
                    const int j = m >> 1, b = m & 1;
                    const int part = n >> 10, hh = (n >> 6) & 15, d = n & 63;
                    if (part == 0) {
                        if (j >= MLEN) {
                            const int qi = j - MLEN;
                            const size_t qidx = (((size_t)(b * NH + hh)) * QLEN + qi) * DH + d;
                            Qac[qidx] = f2bf(v + rwb[hh * DH + d]);
                            Qbd[qidx] = f2bf(v + rrb[hh * DH + d]);
                        }
                    } else if (part == 1) {
                        Kbf[(((size_t)(b * NH + hh)) * KLEN + j) * DH + d] = f2bf(v);
                    } else {
                        Vtb[(((size_t)(b * NH + hh)) * DH + d) * KLEN + j] = f2bf(v);
                    }
                } else {
                    const int hh = n >> 6, d = n & 63;
                    Rh[(((size_t)hh) * KLEN + m) * DH + d] = f2bf(v);
                }
            }
}

// ---------------------------------------------------------------------------
// MFMA flash attention with TransformerXL rel-shift, split-K x2 (contiguous
// halves so the R window slides 64/chunk -> ring buffer).
//
// Round-4: round-3 schedule with staging fixed to the proven wave-uniform
// global_load_lds pattern (HW: LDS dest = wave-uniform base + lane*16;
// a divergent dest pointer is UB -> possible waterfall/hang. All working
// gemm kernels in this file pass w-uniform dests).
//  * Each wave stages 8 rows = 1024 B per call: dest = tile + rowbase*64,
//    rowbase = t*32 + w*8 (uniform); per-lane global row = rowbase + (lane>>3),
//    source granule = (lane&7) ^ (lane>>3)  [T21 source-side XOR swizzle;
//    every rowbase ≡ 0 mod 8 and wb ≡ 0 mod 64, so row&7 == lane>>3].
//  * Fragment reads XOR the same key: granule = (quad | kt*4) ^ (lr&7)
//    -> conflict-minimum b128 reads, no padding (gload_lds needs linear dest).
// Schedule (2 barriers/chunk): barrier vmcnt(0) drains ARE the gloads'
// completion points:
//   B -> issue V gload(c) -> BD/AC/softmax (covers V latency) -> C
//     -> issue K/R gload(c+1) -> PV(c) (covers K/R latency) -> loop
// LDS = Kt 8192 + Rt 16384 + Vl 8192 + Bw 21504 = 54272 B -> 3 blocks/CU.
// ---------------------------------------------------------------------------
__global__ __launch_bounds__(256, 3)
void attn_mfma(const ushort_t* __restrict__ Qac, const ushort_t* __restrict__ Qbd,
               const ushort_t* __restrict__ Kb, const ushort_t* __restrict__ Vt,
               const ushort_t* __restrict__ Rb,
               float* __restrict__ Op0, float* __restrict__ Op1,
               float* __restrict__ Mp, float* __restrict__ Lp)
{
    __shared__ __align__(16) ushort_t Kt[64 * 64];     //  8192 B, swizzled
    __shared__ __align__(16) ushort_t Rt[128 * 64];    // 16384 B, ring, swizzled
    __shared__ __align__(16) ushort_t Vl[64 * 64];     //  8192 B, swizzled
    __shared__ __align__(16) float    Bw[4][16][84];   // 21504 B

    const int tid  = threadIdx.x;
    const int lane = tid & 63;
    const int w    = tid >> 6;
    const int lr   = lane & 15;
    const int quad = lane >> 4;
    const int qt   = blockIdx.x;
    const int s    = blockIdx.y;
    const int bh   = blockIdx.z;
    const int i0   = qt << 6;
    const int h    = bh & 15;
    const int b    = bh >> 4;

    short8 qaf[2], qbf[2];
    {
        const size_t rowoff = ((size_t)bh * QLEN + i0 + w * 16 + lr) * DH;
#pragma unroll
        for (int kt = 0; kt < 2; ++kt) {
            qaf[kt] = *(const short8*)(Qac + rowoff + kt * 32 + quad * 8);
            qbf[kt] = *(const short8*)(Qbd + rowoff + kt * 32 + quad * 8);
        }
    }

    f32x4 O[4];
#pragma unroll
    for (int nt = 0; nt < 4; ++nt) O[nt] = (f32x4){0.f, 0.f, 0.f, 0.f};
    float m_run = -3.4e38f, l_run = 0.f;

    const int nc   = qt + 17;
    const int half = (nc + 1) >> 1;
    const int c_lo = s ? half : 0;
    const int c_hi = s ? nc : half;
    const int stw  = 3 - w;
    const float SC = 0.125f * 1.44269504f;   // scale * log2(e)
    const ushort_t* Kh  = Kb + (size_t)bh * KLEN * DH;
    const ushort_t* Vh  = Vt + (size_t)bh * DH * KLEN;
    const ushort_t* Rhp = Rb + (size_t)h * KLEN * DH;

    // per-lane staging coords (global side); LDS dest stays wave-uniform
    const int lrow = lane >> 3;          // 0..7: row within the wave's 8-row block
    const int lsg  = lane & 7;           // dest granule -> source granule lsg^lrow
    const int sgo  = (lsg ^ lrow) << 3;  // source col offset (ushorts)
    // fragment-read granule offsets (ushorts)
    const int xq   = lr & 7;
    const int fo0  = ((quad ^ xq)) << 3;
    const int fo1  = (((4 | quad) ^ xq)) << 3;

    // ---- prologue: stage K[c_lo] + full 128-row R ring ----
    {
        const int j0 = c_lo << 6;
        const int wb = 960 - i0 + j0;
#pragma unroll
        for (int t = 0; t < 2; ++t) {
            const int rb  = t * 32 + w * 8;           // uniform row base
            gload_lds16(Kh + (size_t)(j0 + rb + lrow) * DH + sgo,
                        Kt + rb * 64);
        }
#pragma unroll
        for (int t = 0; t < 4; ++t) {
            const int gb = wb + t * 32 + w * 8;       // uniform global row base
            const int g  = gb + lrow;
            const int gc = g > (KLEN - 1) ? (KLEN - 1) : g;  // clamped rows feed only masked cells
            gload_lds16(Rhp + (size_t)gc * DH + sgo,
                        Rt + (gb & 127) * 64);
        }
    }

    for (int c = c_lo; c < c_hi; ++c) {
        const int j0 = c << 6;
        const int wb = 960 - i0 + j0;      // window base (global R row of wr=0)

        __syncthreads();   // B: K/R gloads drained -> staging visible

        // issue THIS chunk's V gload (Vl free: PV(c-1) done before B);
        // latency hides under BD/AC/softmax, drained at barrier C
#pragma unroll
        for (int t = 0; t < 2; ++t) {
            const int db = t * 32 + w * 8;            // uniform row base
            gload_lds16(Vh + (size_t)(db + lrow) * KLEN + j0 + sgo,
                        Vl + db * 64);
        }

        // BD: 5 window col-tiles -> Bw (f32)
#pragma unroll
        for (int ctl = 0; ctl < 5; ++ctl) {
            const int wr = (stw + ctl) * 16 + lr;
            const int ring = (wb + wr) & 127;
            f32x4 z = (f32x4){0.f, 0.f, 0.f, 0.f};
            short8 r0 = *(const short8*)&Rt[ring * 64 + fo0];
            z = __builtin_amdgcn_mfma_f32_16x16x32_bf16(qbf[0], r0, z, 0, 0, 0);
            short8 r1 = *(const short8*)&Rt[ring * 64 + fo1];
            z = __builtin_amdgcn_mfma_f32_16x16x32_bf16(qbf[1], r1, z, 0, 0, 0);
#pragma unroll
            for (int rg = 0; rg < 4; ++rg)
                Bw[w][quad * 4 + rg][ctl * 16 + lr] = z[rg];
        }
        // AC: add at shifted col jj + 15 - row
#pragma unroll
        for (int ct = 0; ct < 4; ++ct) {
            f32x4 z = (f32x4){0.f, 0.f, 0.f, 0.f};
            short8 k0f = *(const short8*)&Kt[(ct * 16 + lr) * 64 + fo0];
            z = __builtin_amdgcn_mfma_f32_16x16x32_bf16(qaf[0], k0f, z, 0, 0, 0);
            short8 k1f = *(const short8*)&Kt[(ct * 16 + lr) * 64 + fo1];
            z = __builtin_amdgcn_mfma_f32_16x16x32_bf16(qaf[1], k1f, z, 0, 0, 0);
#pragma unroll
            for (int rg = 0; rg < 4; ++rg) {
                const int rrow = quad * 4 + rg;
                Bw[w][rrow][ct * 16 + lr + 15 - rrow] += z[rg];
            }
        }

        // online softmax; lane's 16 probs == its PV A-fragment
        const int lim = i0 + w * 16 + lr + 1024 - j0;
        float pv[16];
        float mx = -3.4e38f;
#pragma unroll
        for (int kt = 0; kt < 2; ++kt)
#pragma unroll
            for (int t = 0; t < 8; ++t) {
                const int jj = kt * 32 + quad * 8 + t;
                float sv = Bw[w][lr][jj + 15 - lr] * SC;
                sv = (jj > lim) ? -3.4e38f : sv;
                pv[kt * 8 + t] = sv;
                mx = fmaxf(mx, sv);
            }
        mx = fmaxf(mx, __shfl_xor(mx, 16, 64));
        mx = fmaxf(mx, __shfl_xor(mx, 32, 64));
        const float m_new = fmaxf(m_run, mx);
        float ps = 0.f;
        short8 pf[2];
#pragma unroll
        for (int kt = 0; kt < 2; ++kt)
#pragma unroll
            for (int t = 0; t < 8; ++t) {
                const float e = exp2f(pv[kt * 8 + t] - m_new);
                ps += e;
                pf[kt][t] = (short)f2bf(e);
            }
        ps += __shfl_xor(ps, 16, 64);
        ps += __shfl_xor(ps, 32, 64);
        const float alpha = exp2f(m_run - m_new);
        m_run = m_new;
        l_run = l_run * alpha + ps;

        __syncthreads();   // C: V gload drained; Bw/Kt/Rt reads done

        // issue NEXT chunk's K + new R ring rows (Kt readers and the target
        // ring slots' readers finished at C); latency hides under PV,
        // drained at next barrier B
        if (c + 1 < c_hi) {
            const int j1 = j0 + 64;
#pragma unroll
            for (int t = 0; t < 2; ++t) {
                const int rb = t * 32 + w * 8;
                gload_lds16(Kh + (size_t)(j1 + rb + lrow) * DH + sgo,
                            Kt + rb * 64);
            }
#pragma unroll
            for (int t = 0; t < 2; ++t) {
                const int gb = wb + 128 + t * 32 + w * 8;
                const int g  = gb + lrow;
                const int gc = g > (KLEN - 1) ? (KLEN - 1) : g;
                gload_lds16(Rhp + (size_t)gc * DH + sgo,
                            Rt + (gb & 127) * 64);
            }
        }

        float ar[4];
#pragma unroll
        for (int rg = 0; rg < 4; ++rg)
            ar[rg] = __shfl(alpha, quad * 4 + rg, 64);
#pragma unroll
        for (int nt = 0; nt < 4; ++nt) {
            O[nt][0] *= ar[0]; O[nt][1] *= ar[1];
            O[nt][2] *= ar[2]; O[nt][3] *= ar[3];
        }
        {
            short8 vb;
#pragma unroll
            for (int nt = 0; nt < 4; ++nt) {
                vb = *(const short8*)&Vl[(nt * 16 + lr) * 64 + fo0];
                O[nt] = __builtin_amdgcn_mfma_f32_16x16x32_bf16(pf[0], vb, O[nt], 0, 0, 0);
            }
#pragma unroll
            for (int nt = 0; nt < 4; ++nt) {
                vb = *(const short8*)&Vl[(nt * 16 + lr) * 64 + fo1];
                O[nt] = __builtin_amdgcn_mfma_f32_16x16x32_bf16(pf[1], vb, O[nt], 0, 0, 0);
            }
        }
    }

    if (quad == 0) {
        const size_t mi = ((size_t)s * 32 + bh) * QLEN + i0 + w * 16 + lr;
        Mp[mi] = m_run;
        Lp[mi] = l_run;
    }
    float* Op = s ? Op1 : Op0;
#pragma unroll
    for (int nt = 0; nt < 4; ++nt)
#pragma unroll
        for (int rg = 0; rg < 4; ++rg) {
            const int i = i0 + w * 16 + quad * 4 + rg;
            Op[((size_t)i * BSZc + b) * DM + h * DH + nt * 16 + lr] = O[nt][rg];
        }
}

// ---------------------------------------------------------------------------
// merge split-K partials -> bf16 attn_vec
// ---------------------------------------------------------------------------
__global__ __launch_bounds__(256)
void attn_merge(const float* __restrict__ O0, const float* __restrict__ O1,
                const float* __restrict__ Mp, const float* __restrict__ Lp,
                ushort_t* __restrict__ AV)
{
    const int row = blockIdx.x;           // i*BSZ + b
    const int tid = threadIdx.x;
    const int i = row >> 1, b = row & 1;
    const int h = tid >> 4;
    const int bh = b * NH + h;
    const size_t mi = (size_t)bh * QLEN + i;
    const float m1 = Mp[mi],             l1 = Lp[mi];
    const float m2 = Mp[32 * QLEN + mi], l2 = Lp[32 * QLEN + mi];
    const float M = fmaxf(m1, m2);
    const float a1 = exp2f(m1 - M), a2 = exp2f(m2 - M);
    const float rl = 1.f / (l1 * a1 + l2 * a2);
    const float f1 = a1 * rl, f2 = a2 * rl;
    const float4 o1 = ((const float4*)(O0 + (size_t)row * DM))[tid];
    const float4 o2 = ((const float4*)(O1 + (size_t)row * DM))[tid];
    ushort_t* p = AV + (size_t)row * DM + tid * 4;
    p[0] = f2bf(o1.x * f1 + o2.x * f2);
    p[1] = f2bf(o1.y * f1 + o2.y * f2);
    p[2] = f2bf(o1.z * f1 + o2.z * f2);
    p[3] = f2bf(o1.w * f1 + o2.w * f2);
}

// ---------------------------------------------------------------------------
// out = LayerNorm(X + Y0 [+ Y1]); optional bf16 secondary output
// ---------------------------------------------------------------------------
__global__ __launch_bounds__(256)
void add_ln(const float* __restrict__ X, const float* __restrict__ Y0,
            const float* __restrict__ Y1,
            const float* __restrict__ gg, const float* __restrict__ bb,
            float* __restrict__ out, ushort_t* __restrict__ outb)
{
    const int row  = blockIdx.x;
    const int tid  = threadIdx.x;
    const int lane = tid & 63;
    const int w    = tid >> 6;
    __shared__ float ssum[4], ssq[4];

    const float4 xv = ((const float4*)(X + (size_t)row * DM))[tid];
    const float4 yv = ((const float4*)(Y0 + (size_t)row * DM))[tid];
    float v0 = xv.x + yv.x, v1 = xv.y + yv.y;
    float v2 = xv.z + yv.z, v3 = xv.w + yv.w;
    if (Y1) {
        const float4 zv = ((const float4*)(Y1 + (size_t)row * DM))[tid];
        v0 += zv.x; v1 += zv.y; v2 += zv.z; v3 += zv.w;
    }
    float s = v0 + v1 + v2 + v3;
    float q = v0 * v0 + v1 * v1 + v2 * v2 + v3 * v3;
#pragma unroll
    for (int off = 32; off > 0; off >>= 1) {
        s += __shfl_xor(s, off, 64);
        q += __shfl_xor(q, off, 64);
    }
    if (lane == 0) { ssum[w] = s; ssq[w] = q; }
    __syncthreads();
    s = ssum[0] + ssum[1] + ssum[2] + ssum[3];
    q = ssq[0] + ssq[1] + ssq[2] + ssq[3];
    const float mean = s * (1.f / DM);
    const float var  = q * (1.f / DM) - mean * mean;
    const float rs   = rsqrtf(var + 1e-5f);
    const float4 g4 = ((const float4*)gg)[tid];
    const float4 b4 = ((const float4*)bb)[tid];
    float4 ov;
    ov.x = (v0 - mean) * rs * g4.x + b4.x;
    ov.y = (v1 - mean) * rs * g4.y + b4.y;
    ov.z = (v2 - mean) * rs * g4.z + b4.z;
    ov.w = (v3 - mean) * rs * g4.w + b4.w;
    ((float4*)(out + (size_t)row * DM))[tid] = ov;
    if (outb) {
        ushort_t* p = outb + (size_t)row * DM + tid * 4;
        p[0] = f2bf(ov.x); p[1] = f2bf(ov.y);
        p[2] = f2bf(ov.z); p[3] = f2bf(ov.w);
    }
}

// ---------------------------------------------------------------------------
extern "C" void kernel_launch(void* const* d_in, const int* in_sizes, int n_in,
                              void* d_out, int out_size, void* d_ws, size_t ws_size,
                              hipStream_t stream)
{
    (void)in_sizes; (void)n_in; (void)out_size; (void)ws_size;
    const float* w      = (const float*)d_in[0];
    const float* r      = (const float*)d_in[1];
    const float* mems   = (const float*)d_in[2];
    // d_in[3] attn_mask: deterministic (j > i + MLEN), applied analytically
    const float* qkv_w  = (const float*)d_in[4];
    const float* rnet_w = (const float*)d_in[5];
    const float* o_w    = (const float*)d_in[6];
    const float* r_r_b  = (const float*)d_in[7];
    const float* r_w_b  = (const float*)d_in[8];
    const float* ln1g   = (const float*)d_in[9];
    const float* ln1b   = (const float*)d_in[10];
    const float* ffw1   = (const float*)d_in[11];
    const float* ffb1   = (const float*)d_in[12];
    const float* ffw2   = (const float*)d_in[13];
    const float* ffb2   = (const float*)d_in[14];
    const float* ln2g   = (const float*)d_in[15];
    const float* ln2b   = (const float*)d_in[16];
    float* out = (float*)d_out;

    char* wsb = (char*)d_ws;
    const size_t MB = 1024 * 1024;
    // ---- workspace layout, live ranges verified against launch order ----
    ushort_t* W1    = (ushort_t*)(wsb + 0 * MB);   // 0-6    dead after qkvr
    ushort_t* W2    = (ushort_t*)(wsb + 6 * MB);   // 6-8    dead after qkvr
    ushort_t* Acat  = (ushort_t*)(wsb + 8 * MB);   // 8-16   dead after qkvr
    ushort_t* Rsrc  = (ushort_t*)(wsb + 16 * MB);  // 16-20  dead after qkvr
    ushort_t* Qac   = (ushort_t*)(wsb + 20 * MB);  // 20-24  dead after attn
    ushort_t* Qbd   = (ushort_t*)(wsb + 24 * MB);  // 24-28  dead after attn
    ushort_t* Kbf   = (ushort_t*)(wsb + 28 * MB);  // 28-36  dead after attn
    ushort_t* Vt    = (ushort_t*)(wsb + 36 * MB);  // 36-44  dead after attn
    ushort_t* Rh    = (ushort_t*)(wsb + 44 * MB);  // 44-48  dead after attn
    float*    Op0   = (float*)(wsb + 48 * MB);     // 48-56  attn -> merge
    float*    Op1   = (float*)(wsb + 56 * MB);     // 56-64  attn -> merge
    float*    Mp    = (float*)(wsb + 4 * MB);      // 4-4.25 (over dead W1)
    float*    Lp    = (float*)(wsb + 4 * MB + 512 * 1024); // 4.5-4.75
    ushort_t* AVec  = (ushort_t*)(wsb + 0 * MB);   // 0-4   merge -> o-proj
    ushort_t* W3    = (ushort_t*)(wsb + 4 * MB);   // 4-6   cast2 -> o-proj (over Mp/Lp dead)
    float*    AOut0 = (float*)(wsb + 8 * MB);      // 8-16  o-proj -> ln1 (over Acat dead)
    float*    AOut1 = (float*)(wsb + 44 * MB);     // 44-52 o-proj -> ln1 (over Rh/Op0-head dead)
    float*    Hbuf  = (float*)(wsb + 16 * MB);     // 16-24 ln1 -> ln2 (over Rsrc/Qac dead)
    ushort_t* Hbf   = (ushort_t*)(wsb + 24 * MB);  // 24-28 ln1 -> ff1 (over Qbd dead)
    ushort_t* W4    = (ushort_t*)(wsb + 28 * MB);  // 28-36 cast2 -> ff1 (over Kbf dead)
    ushort_t* FFbf  = (ushort_t*)(wsb + 36 * MB);  // 36-52 ff1 -> ff2 (over Vt/AOut1 dead)
    ushort_t* W5    = (ushort_t*)(wsb + 52 * MB);  // 52-60 cast2 -> ff2 (over Op0-tail/Op1-head dead)
    float*    Core0 = (float*)(wsb + 0 * MB);      // 0-8   ff2 -> ln2 (AVec/W3 dead)
    float*    Core1 = (float*)(wsb + 8 * MB);      // 8-16  ff2 -> ln2 (AOut0 dead)
    // peak 64 MB

    dim3 blk(256);

    // casts for phase 1
    cast_phase1<<<dim3(5120), blk, 0, stream>>>(qkv_w, rnet_w, mems, w, r,
                                                W1, W2, Acat, Rsrc);

    // 1+2. fused QKV + r_net projections
    gemm_qkvr<<<dim3(896), blk, 0, stream>>>(
        Acat, W1, Rsrc, W2, Qac, Qbd, Kbf, Vt, Rh, r_w_b, r_r_b);

    // 3. MFMA flash attention, split-K x2 (contiguous halves) -> partials
    attn_mfma<<<dim3(16, 2, 32), blk, 0, stream>>>(
        Qac, Qbd, Kbf, Vt, Rh, Op0, Op1, Mp, Lp);

    // 3b. merge partials -> bf16 attn_vec
    attn_merge<<<dim3(2048), blk, 0, stream>>>(Op0, Op1, Mp, Lp, AVec);

    // casts for phase 2
    cast_phase2<<<dim3(4608), blk, 0, stream>>>(o_w, ffw1, ffw2, W3, W4, W5);

    // 4. output projection, split-K x2 (f32 partials)
    gemm_mfma<0, 0, 64, 2><<<dim3(16, 16, 2), blk, 0, stream>>>(
        AVec, W3, nullptr, AOut0, AOut1, 2048, 1024, 512, 1024, 1024);

    // 5. h = LN(w + AOut0 + AOut1)  (f32 + bf16 copies)
    add_ln<<<dim3(2 * QLEN), blk, 0, stream>>>(w, AOut0, AOut1, ln1g, ln1b, Hbuf, Hbf);

    // 6. FF1: relu(h @ ff_w1^T + b1) -> bf16
    gemm_mfma<3, 1, 128, 1><<<dim3(16, 32), blk, 0, stream>>>(
        Hbf, W4, ffb1, FFbf, nullptr, 2048, 4096, 1024, 1024, 1024);

    // 7. FF2, split-K x2 -> f32 partials
    gemm_mfma<0, 0, 64, 2><<<dim3(16, 16, 2), blk, 0, stream>>>(
        FFbf, W5, ffb2, Core0, Core1, 2048, 1024, 2048, 4096, 4096);

    // 8. out = LN(h + Core0 + Core1)
    add_ln<<<dim3(2 * QLEN), blk, 0, stream>>>(Hbuf, Core0, Core1, ln2g, ln2b, out, nullptr);
}

// Round 5
// 391.337 us; speedup vs baseline: 1.1571x; 1.0069x over previous
//
#include <hip/hip_runtime.h>
#include <math.h>

#define QLEN 1024
#define MLEN 1024
#define KLEN 2048
#define BSZc 2
#define NH 16
#define DH 64
#define DM 1024
#define DI 4096

typedef unsigned short ushort_t;
typedef __attribute__((ext_vector_type(8))) short short8;
typedef __attribute__((ext_vector_type(4))) float f32x4;

__device__ __forceinline__ ushort_t f2bf(float x) {
    unsigned int u = __float_as_uint(x);
    unsigned int r = (u + 0x7FFFu + ((u >> 16) & 1u)) >> 16;
    return (ushort_t)r;
}

__device__ __forceinline__ void gload_lds16(const ushort_t* g, ushort_t* l) {
    __builtin_amdgcn_global_load_lds(
        (const __attribute__((address_space(1))) unsigned int*)g,
        (__attribute__((address_space(3))) unsigned int*)l,
        16, 0, 0);
}

// ---------------------------------------------------------------------------
// segmented f32 -> bf16 casts (one launch per phase)
// ---------------------------------------------------------------------------
__device__ __forceinline__ void cast8(const float* s, ushort_t* d, int g) {
    const float4 a = *(const float4*)(s + g * 8);
    const float4 b = *(const float4*)(s + g * 8 + 4);
    short8 o;
    o[0] = (short)f2bf(a.x); o[1] = (short)f2bf(a.y);
    o[2] = (short)f2bf(a.z); o[3] = (short)f2bf(a.w);
    o[4] = (short)f2bf(b.x); o[5] = (short)f2bf(b.y);
    o[6] = (short)f2bf(b.z); o[7] = (short)f2bf(b.w);
    *(short8*)(d + g * 8) = o;
}

__global__ __launch_bounds__(256)
void cast_phase1(const float* __restrict__ qkv_w, const float* __restrict__ rnet_w,
                 const float* __restrict__ mems, const float* __restrict__ w,
                 const float* __restrict__ r,
                 ushort_t* __restrict__ W1, ushort_t* __restrict__ W2,
                 ushort_t* __restrict__ Acat, ushort_t* __restrict__ Rsrc)
{
    int g = blockIdx.x * 256 + threadIdx.x;
    if (g < 393216)            { cast8(qkv_w,  W1,              g); }
    else if (g < 524288)       { cast8(rnet_w, W2,              g - 393216); }
    else if (g < 786432)       { cast8(mems,   Acat,            g - 524288); }
    else if (g < 1048576)      { cast8(w,      Acat + 2097152,  g - 786432); }
    else if (g < 1310720)      { cast8(r,      Rsrc,            g - 1048576); }
}

__global__ __launch_bounds__(256)
void cast_phase2(const float* __restrict__ o_w, const float* __restrict__ ffw1,
                 const float* __restrict__ ffw2,
                 ushort_t* __restrict__ W3, ushort_t* __restrict__ W4,
                 ushort_t* __restrict__ W5)
{
    int g = blockIdx.x * 256 + threadIdx.x;
    if (g < 131072)            { cast8(o_w,  W3, g); }
    else if (g < 655360)       { cast8(ffw1, W4, g - 131072); }
    else if (g < 1179648)      { cast8(ffw2, W5, g - 655360); }
}

// ---------------------------------------------------------------------------
// bf16 MFMA GEMM: C = A @ B^T. 128 x BN tile, BK=64 (two BK=32 buffer pairs).
// SPLIT>1: blockIdx.z selects K-slice; partial f32 out; bias only on z==0.
// EMODE 0: f32 out (+bias). EMODE 3: bf16 out (+bias, +relu if ACT).
// ---------------------------------------------------------------------------
template<int EMODE, int ACT, int BN, int SPLIT>
__global__ __launch_bounds__(256)
void gemm_mfma(const ushort_t* __restrict__ A, const ushort_t* __restrict__ B,
               const float* __restrict__ bias,
               void* __restrict__ O0v, void* __restrict__ O1v,
               int M, int N, int Ks, int lda, int ldb)
{
    constexpr int JT = BN / 32;
    __shared__ ushort_t At0[128 * 32];
    __shared__ ushort_t At1[128 * 32];
    __shared__ ushort_t Bt0[BN * 32];
    __shared__ ushort_t Bt1[BN * 32];

    const int tid  = threadIdx.x;
    const int lane = tid & 63;
    const int w    = tid >> 6;
    const int lr   = lane & 15;
    const int quad = lane >> 4;
    const int m0   = blockIdx.x * 128;
    const int n0   = blockIdx.y * BN;
    const int z    = (SPLIT > 1) ? (int)blockIdx.z : 0;
    const int kbase = z * Ks;
    const int wm0  = (w >> 1) * 64;
    const int wn0  = (w & 1) * (BN / 2);

    f32x4 acc[4][JT];
#pragma unroll
    for (int it = 0; it < 4; ++it)
#pragma unroll
        for (int jt = 0; jt < JT; ++jt) acc[it][jt] = (f32x4){0.f, 0.f, 0.f, 0.f};

    const int srow = lane >> 2;
    const int scol = (lane & 3) << 3;
    const ushort_t* Ag = A + (size_t)(m0 + w * 32 + srow) * lda + kbase + scol;
    ushort_t* a00 = At0 + (w * 32) * 32;
    ushort_t* a01 = At0 + (w * 32 + 16) * 32;
    ushort_t* a10 = At1 + (w * 32) * 32;
    ushort_t* a11 = At1 + (w * 32 + 16) * 32;
    const ushort_t* Bg;
    ushort_t *b00, *b01 = nullptr, *b10, *b11 = nullptr;
    if (BN == 128) {
        Bg  = B + (size_t)(n0 + w * 32 + srow) * ldb + kbase + scol;
        b00 = Bt0 + (w * 32) * 32;
        b01 = Bt0 + (w * 32 + 16) * 32;
        b10 = Bt1 + (w * 32) * 32;
        b11 = Bt1 + (w * 32 + 16) * 32;
    } else {
        Bg  = B + (size_t)(n0 + w * 16 + srow) * ldb + kbase + scol;
        b00 = Bt0 + (w * 16) * 32;
        b10 = Bt1 + (w * 16) * 32;
    }

    const ushort_t* Ato0 = At0 + (wm0 + lr) * 32 + quad * 8;
    const ushort_t* Ato1 = At1 + (wm0 + lr) * 32 + quad * 8;
    const ushort_t* Bto0 = Bt0 + (wn0 + lr) * 32 + quad * 8;
    const ushort_t* Bto1 = Bt1 + (wn0 + lr) * 32 + quad * 8;

    for (int k0 = 0; k0 < Ks; k0 += 64) {
        __syncthreads();
        gload_lds16(Ag + k0, a00);
        gload_lds16(Ag + (size_t)16 * lda + k0, a01);
        gload_lds16(Ag + k0 + 32, a10);
        gload_lds16(Ag + (size_t)16 * lda + k0 + 32, a11);
        if (BN == 128) {
            gload_lds16(Bg + k0, b00);
            gload_lds16(Bg + (size_t)16 * ldb + k0, b01);
            gload_lds16(Bg + k0 + 32, b10);
            gload_lds16(Bg + (size_t)16 * ldb + k0 + 32, b11);
        } else {
            gload_lds16(Bg + k0, b00);
            gload_lds16(Bg + k0 + 32, b10);
        }
        __syncthreads();

        short8 af[4], bf[JT];
#pragma unroll
        for (int it = 0; it < 4; ++it)
            af[it] = *(const short8*)(Ato0 + it * 16 * 32);
#pragma unroll
        for (int jt = 0; jt < JT; ++jt)
            bf[jt] = *(const short8*)(Bto0 + jt * 16 * 32);
#pragma unroll
        for (int it = 0; it < 4; ++it)
#pragma unroll
            for (int jt = 0; jt < JT; ++jt)
                acc[it][jt] = __builtin_amdgcn_mfma_f32_16x16x32_bf16(
                    af[it], bf[jt], acc[it][jt], 0, 0, 0);
#pragma unroll
        for (int it = 0; it < 4; ++it)
            af[it] = *(const short8*)(Ato1 + it * 16 * 32);
#pragma unroll
        for (int jt = 0; jt < JT; ++jt)
            bf[jt] = *(const short8*)(Bto1 + jt * 16 * 32);
#pragma unroll
        for (int it = 0; it < 4; ++it)
#pragma unroll
            for (int jt = 0; jt < JT; ++jt)
                acc[it][jt] = __builtin_amdgcn_mfma_f32_16x16x32_bf16(
                    af[it], bf[jt], acc[it][jt], 0, 0, 0);
    }

#pragma unroll
    for (int it = 0; it < 4; ++it)
#pragma unroll
        for (int jt = 0; jt < JT; ++jt)
#pragma unroll
            for (int rg = 0; rg < 4; ++rg) {
                const int m = m0 + wm0 + it * 16 + quad * 4 + rg;
                const int n = n0 + wn0 + jt * 16 + lr;
                float v = acc[it][jt][rg];
                if (EMODE == 0) {
                    float* dst = (float*)(z ? O1v : O0v);
                    if (bias && z == 0) v += bias[n];
                    dst[(size_t)m * N + n] = v;
                } else {
                    v += bias[n];
                    if (ACT == 1) v = fmaxf(v, 0.f);
                    ((ushort_t*)O0v)[(size_t)m * N + n] = f2bf(v);
                }
            }
}

// ---------------------------------------------------------------------------
// Fused QKV + r_net GEMM — round-5: K-loop ported to the proven gemm_mfma
// BK=64 structure (two BK=32 buffer pairs, 32 MFMA per staging round,
// half the barriers of the old BK=32 loop). Epilogue scatter unchanged.
// ---------------------------------------------------------------------------
__global__ __launch_bounds__(256)
void gemm_qkvr(const ushort_t* __restrict__ Acat, const ushort_t* __restrict__ W1,
               const ushort_t* __restrict__ Rsrc, const ushort_t* __restrict__ W2,
               ushort_t* __restrict__ Qac, ushort_t* __restrict__ Qbd,
               ushort_t* __restrict__ Kbf, ushort_t* __restrict__ Vtb,
               ushort_t* __restrict__ Rh,
               const float* __restrict__ rwb, const float* __restrict__ rrb)
{
    __shared__ ushort_t At0[128 * 32];
    __shared__ ushort_t At1[128 * 32];
    __shared__ ushort_t Bt0[128 * 32];
    __shared__ ushort_t Bt1[128 * 32];

    const int bid  = blockIdx.x;
    const bool isr = bid >= 768;
    const ushort_t* A; const ushort_t* B; int m0, n0;
    if (!isr) { A = Acat; B = W1; m0 = (bid & 31) * 128; n0 = (bid >> 5) * 128; }
    else { int t = bid - 768; A = Rsrc; B = W2; m0 = (t & 15) * 128; n0 = (t >> 4) * 128; }
    const int K = 1024;

    const int tid  = threadIdx.x;
    const int lane = tid & 63;
    const int w    = tid >> 6;
    const int lr   = lane & 15;
    const int quad = lane >> 4;
    const int wm0  = (w >> 1) * 64;
    const int wn0  = (w & 1) * 64;

    f32x4 acc[4][4];
#pragma unroll
    for (int it = 0; it < 4; ++it)
#pragma unroll
        for (int jt = 0; jt < 4; ++jt) acc[it][jt] = (f32x4){0.f, 0.f, 0.f, 0.f};

    const int srow = lane >> 2;
    const int scol = (lane & 3) << 3;
    const ushort_t* Ag = A + (size_t)(m0 + w * 32 + srow) * K + scol;
    const ushort_t* Bg = B + (size_t)(n0 + w * 32 + srow) * K + scol;
    ushort_t* a00 = At0 + (w * 32) * 32;
    ushort_t* a01 = At0 + (w * 32 + 16) * 32;
    ushort_t* a10 = At1 + (w * 32) * 32;
    ushort_t* a11 = At1 + (w * 32 + 16) * 32;
    ushort_t* b00 = Bt0 + (w * 32) * 32;
    ushort_t* b01 = Bt0 + (w * 32 + 16) * 32;
    ushort_t* b10 = Bt1 + (w * 32) * 32;
    ushort_t* b11 = Bt1 + (w * 32 + 16) * 32;

    const ushort_t* Ato0 = At0 + (wm0 + lr) * 32 + quad * 8;
    const ushort_t* Ato1 = At1 + (wm0 + lr) * 32 + quad * 8;
    const ushort_t* Bto0 = Bt0 + (wn0 + lr) * 32 + quad * 8;
    const ushort_t* Bto1 = Bt1 + (wn0 + lr) * 32 + quad * 8;

    for (int k0 = 0; k0 < K; k0 += 64) {
        __syncthreads();
        gload_lds16(Ag + k0, a00);
        gload_lds16(Ag + (size_t)16 * K + k0, a01);
        gload_lds16(Ag + k0 + 32, a10);
        gload_lds16(Ag + (size_t)16 * K + k0 + 32, a11);
        gload_lds16(Bg + k0, b00);
        gload_lds16(Bg + (size_t)16 * K + k0, b01);
        gload_lds16(Bg + k0 + 32, b10);
        gload_lds16(Bg + (size_t)16 * K + k0 + 32, b11);
        __syncthreads();

        short8 af[4], bf[4];
#pragma unroll
        for (int it = 0; it < 4; ++it)
            af[it] = *(const short8*)(Ato0 + it * 16 * 32);
#pragma unroll
        for (int jt = 0; jt < 4; ++jt)
            bf[jt] = *(const short8*)(Bto0 + jt * 16 * 32);
#pragma unroll
        for (int it = 0; it < 4; ++it)
#pragma unroll
            for (int jt = 0; jt < 4; ++jt)
                acc[it][jt] = __builtin_amdgcn_mfma_f32_16x16x32_bf16(
                    af[it], bf[jt], acc[it][jt], 0, 0, 0);
#pragma unroll
        for (int it = 0; it < 4; ++it)
            af[it] = *(const short8*)(Ato1 + it * 16 * 32);
#pragma unroll
        for (int jt = 0; jt < 4; ++jt)
            bf[jt] = *(const short8*)(Bto1 + jt * 16 * 32);
#pragma unroll
        for (int it = 0; it < 4; ++it)
#pragma unroll
            for (int jt = 0; jt < 4; ++jt)
                acc[it][jt] = __builtin_amdgcn_mfma_f32_16x16x32_bf16(
                    af[it], bf[jt], acc[it][jt], 0, 0, 0);
    }

#pragma unroll
    for (int it = 0; it < 4; ++it)
#pragma unroll
        for (int jt = 0; jt < 4; ++jt)
#pragma unroll
            for (int rg = 0; rg < 4; ++rg) {
                const int m = m0 + wm0 + it * 16 + quad * 4 + rg;
                const int n = n0 + wn0 + jt * 16 + lr;
                const float v = acc[it][jt][rg];
                if (!isr) {
                    const int j = m >> 1, b = m & 1;
                    const int part = n >> 10, hh = (n >> 6) & 15, d = n & 63;
                    if (part == 0) {
                        if (j >= MLEN) {
                            const int qi = j - MLEN;
                            const size_t qidx = (((size_t)(b * NH + hh)) * QLEN + qi) * DH + d;
                            Qac[qidx] = f2bf(v + rwb[hh * DH + d]);
                            Qbd[qidx] = f2bf(v + rrb[hh * DH + d]);
                        }
                    } else if (part == 1) {
                        Kbf[(((size_t)(b * NH + hh)) * KLEN + j) * DH + d] = f2bf(v);
                    } else {
                        Vtb[(((size_t)(b * NH + hh)) * DH + d) * KLEN + j] = f2bf(v);
                    }
                } else {
                    const int hh = n >> 6, d = n & 63;
                    Rh[(((size_t)hh) * KLEN + m) * DH + d] = f2bf(v);
                }
            }
}

// ---------------------------------------------------------------------------
// MFMA flash attention with TransformerXL rel-shift, split-K x2 (contiguous
// halves so the R window slides 64/chunk -> ring buffer).
//
// Round-4 (verified): wave-uniform global_load_lds staging (dest = uniform
// base; per-lane global row = base + lane>>3, source granule (lane&7)^(lane>>3)
// = T21 source-side XOR swizzle), fragment reads XOR the same key.
// Schedule (2 barriers/chunk): barrier vmcnt(0) drains ARE the gloads'
// completion points:
//   B -> issue V gload(c) -> BD/AC/softmax (covers V latency) -> C
//     -> issue K/R gload(c+1) -> PV(c) (covers K/R latency) -> loop
// LDS = Kt 8192 + Rt 16384 + Vl 8192 + Bw 21504 = 54272 B -> 3 blocks/CU.
// ---------------------------------------------------------------------------
__global__ __launch_bounds__(256, 3)
void attn_mfma(const ushort_t* __restrict__ Qac, const ushort_t* __restrict__ Qbd,
               const ushort_t* __restrict__ Kb, const ushort_t* __restrict__ Vt,
               const ushort_t* __restrict__ Rb,
               float* __restrict__ Op0, float* __restrict__ Op1,
               float* __restrict__ Mp, float* __restrict__ Lp)
{
    __shared__ __align__(16) ushort_t Kt[64 * 64];     //  8192 B, swizzled
    __shared__ __align__(16) ushort_t Rt[128 * 64];    // 16384 B, ring, swizzled
    __shared__ __align__(16) ushort_t Vl[64 * 64];     //  8192 B, swizzled
    __shared__ __align__(16) float    Bw[4][16][84];   // 21504 B

    const int tid  = threadIdx.x;
    const int lane = tid & 63;
    const int w    = tid >> 6;
    const int lr   = lane & 15;
    const int quad = lane >> 4;
    const int qt   = blockIdx.x;
    const int s    = blockIdx.y;
    const int bh   = blockIdx.z;
    const int i0   = qt << 6;
    const int h    = bh & 15;
    const int b    = bh >> 4;

    short8 qaf[2], qbf[2];
    {
        const size_t rowoff = ((size_t)bh * QLEN + i0 + w * 16 + lr) * DH;
#pragma unroll
        for (int kt = 0; kt < 2; ++kt) {
            qaf[kt] = *(const short8*)(Qac + rowoff + kt * 32 + quad * 8);
            qbf[kt] = *(const short8*)(Qbd + rowoff + kt * 32 + quad * 8);
        }
    }

    f32x4 O[4];
#pragma unroll
    for (int nt = 0; nt < 4; ++nt) O[nt] = (f32x4){0.f, 0.f, 0.f, 0.f};
    float m_run = -3.4e38f, l_run = 0.f;

    const int nc   = qt + 17;
    const int half = (nc + 1) >> 1;
    const int c_lo = s ? half : 0;
    const int c_hi = s ? nc : half;
    const int stw  = 3 - w;
    const float SC = 0.125f * 1.44269504f;   // scale * log2(e)
    const ushort_t* Kh  = Kb + (size_t)bh * KLEN * DH;
    const ushort_t* Vh  = Vt + (size_t)bh * DH * KLEN;
    const ushort_t* Rhp = Rb + (size_t)h * KLEN * DH;

    // per-lane staging coords (global side); LDS dest stays wave-uniform
    const int lrow = lane >> 3;          // 0..7: row within the wave's 8-row block
    const int lsg  = lane & 7;           // dest granule -> source granule lsg^lrow
    const int sgo  = (lsg ^ lrow) << 3;  // source col offset (ushorts)
    // fragment-read granule offsets (ushorts)
    const int xq   = lr & 7;
    const int fo0  = ((quad ^ xq)) << 3;
    const int fo1  = (((4 | quad) ^ xq)) << 3;

    // ---- prologue: stage K[c_lo] + full 128-row R ring ----
    {
        const int j0 = c_lo << 6;
        const int wb = 960 - i0 + j0;
#pragma unroll
        for (int t = 0; t < 2; ++t) {
            const int rb  = t * 32 + w * 8;           // uniform row base
            gload_lds16(Kh + (size_t)(j0 + rb + lrow) * DH + sgo,
                        Kt + rb * 64);
        }
#pragma unroll
        for (int t = 0; t < 4; ++t) {
            const int gb = wb + t * 32 + w * 8;       // uniform global row base
            const int g  = gb + lrow;
            const int gc = g > (KLEN - 1) ? (KLEN - 1) : g;  // clamped rows feed only masked cells
            gload_lds16(Rhp + (size_t)gc * DH + sgo,
                        Rt + (gb & 127) * 64);
        }
    }

    for (int c = c_lo; c < c_hi; ++c) {
        const int j0 = c << 6;
        const int wb = 960 - i0 + j0;      // window base (global R row of wr=0)

        __syncthreads();   // B: K/R gloads drained -> staging visible

        // issue THIS chunk's V gload (Vl free: PV(c-1) done before B);
        // latency hides under BD/AC/softmax, drained at barrier C
#pragma unroll
        for (int t = 0; t < 2; ++t) {
            const int db = t * 32 + w * 8;            // uniform row base
            gload_lds16(Vh + (size_t)(db + lrow) * KLEN + j0 + sgo,
                        Vl + db * 64);
        }

        // BD: 5 window col-tiles -> Bw (f32)
#pragma unroll
        for (int ctl = 0; ctl < 5; ++ctl) {
            const int wr = (stw + ctl) * 16 + lr;
            const int ring = (wb + wr) & 127;
            f32x4 z = (f32x4){0.f, 0.f, 0.f, 0.f};
            short8 r0 = *(const short8*)&Rt[ring * 64 + fo0];
            z = __builtin_amdgcn_mfma_f32_16x16x32_bf16(qbf[0], r0, z, 0, 0, 0);
            short8 r1 = *(const short8*)&Rt[ring * 64 + fo1];
            z = __builtin_amdgcn_mfma_f32_16x16x32_bf16(qbf[1], r1, z, 0, 0, 0);
#pragma unroll
            for (int rg = 0; rg < 4; ++rg)
                Bw[w][quad * 4 + rg][ctl * 16 + lr] = z[rg];
        }
        // AC: add at shifted col jj + 15 - row
#pragma unroll
        for (int ct = 0; ct < 4; ++ct) {
            f32x4 z = (f32x4){0.f, 0.f, 0.f, 0.f};
            short8 k0f = *(const short8*)&Kt[(ct * 16 + lr) * 64 + fo0];
            z = __builtin_amdgcn_mfma_f32_16x16x32_bf16(qaf[0], k0f, z, 0, 0, 0);
            short8 k1f = *(const short8*)&Kt[(ct * 16 + lr) * 64 + fo1];
            z = __builtin_amdgcn_mfma_f32_16x16x32_bf16(qaf[1], k1f, z, 0, 0, 0);
#pragma unroll
            for (int rg = 0; rg < 4; ++rg) {
                const int rrow = quad * 4 + rg;
                Bw[w][rrow][ct * 16 + lr + 15 - rrow] += z[rg];
            }
        }

        // online softmax; lane's 16 probs == its PV A-fragment
        const int lim = i0 + w * 16 + lr + 1024 - j0;
        float pv[16];
        float mx = -3.4e38f;
#pragma unroll
        for (int kt = 0; kt < 2; ++kt)
#pragma unroll
            for (int t = 0; t < 8; ++t) {
                const int jj = kt * 32 + quad * 8 + t;
                float sv = Bw[w][lr][jj + 15 - lr] * SC;
                sv = (jj > lim) ? -3.4e38f : sv;
                pv[kt * 8 + t] = sv;
                mx = fmaxf(mx, sv);
            }
        mx = fmaxf(mx, __shfl_xor(mx, 16, 64));
        mx = fmaxf(mx, __shfl_xor(mx, 32, 64));
        const float m_new = fmaxf(m_run, mx);
        float ps = 0.f;
        short8 pf[2];
#pragma unroll
        for (int kt = 0; kt < 2; ++kt)
#pragma unroll
            for (int t = 0; t < 8; ++t) {
                const float e = exp2f(pv[kt * 8 + t] - m_new);
                ps += e;
                pf[kt][t] = (short)f2bf(e);
            }
        ps += __shfl_xor(ps, 16, 64);
        ps += __shfl_xor(ps, 32, 64);
        const float alpha = exp2f(m_run - m_new);
        m_run = m_new;
        l_run = l_run * alpha + ps;

        __syncthreads();   // C: V gload drained; Bw/Kt/Rt reads done

        // issue NEXT chunk's K + new R ring rows (Kt readers and the target
        // ring slots' readers finished at C); latency hides under PV,
        // drained at next barrier B
        if (c + 1 < c_hi) {
            const int j1 = j0 + 64;
#pragma unroll
            for (int t = 0; t < 2; ++t) {
                const int rb = t * 32 + w * 8;
                gload_lds16(Kh + (size_t)(j1 + rb + lrow) * DH + sgo,
                            Kt + rb * 64);
            }
#pragma unroll
            for (int t = 0; t < 2; ++t) {
                const int gb = wb + 128 + t * 32 + w * 8;
                const int g  = gb + lrow;
                const int gc = g > (KLEN - 1) ? (KLEN - 1) : g;
                gload_lds16(Rhp + (size_t)gc * DH + sgo,
                            Rt + (gb & 127) * 64);
            }
        }

        float ar[4];
#pragma unroll
        for (int rg = 0; rg < 4; ++rg)
            ar[rg] = __shfl(alpha, quad * 4 + rg, 64);
#pragma unroll
        for (int nt = 0; nt < 4; ++nt) {
            O[nt][0] *= ar[0]; O[nt][1] *= ar[1];
            O[nt][2] *= ar[2]; O[nt][3] *= ar[3];
        }
        {
            short8 vb;
#pragma unroll
            for (int nt = 0; nt < 4; ++nt) {
                vb = *(const short8*)&Vl[(nt * 16 + lr) * 64 + fo0];
                O[nt] = __builtin_amdgcn_mfma_f32_16x16x32_bf16(pf[0], vb, O[nt], 0, 0, 0);
            }
#pragma unroll
            for (int nt = 0; nt < 4; ++nt) {
                vb = *(const short8*)&Vl[(nt * 16 + lr) * 64 + fo1];
                O[nt] = __builtin_amdgcn_mfma_f32_16x16x32_bf16(pf[1], vb, O[nt], 0, 0, 0);
            }
        }
    }

    if (quad == 0) {
        const size_t mi = ((size_t)s * 32 + bh) * QLEN + i0 + w * 16 + lr;
        Mp[mi] = m_run;
        Lp[mi] = l_run;
    }
    float* Op = s ? Op1 : Op0;
#pragma unroll
    for (int nt = 0; nt < 4; ++nt)
#pragma unroll
        for (int rg = 0; rg < 4; ++rg) {
            const int i = i0 + w * 16 + quad * 4 + rg;
            Op[((size_t)i * BSZc + b) * DM + h * DH + nt * 16 + lr] = O[nt][rg];
        }
}

// ---------------------------------------------------------------------------
// merge split-K partials -> bf16 attn_vec
// ---------------------------------------------------------------------------
__global__ __launch_bounds__(256)
void attn_merge(const float* __restrict__ O0, const float* __restrict__ O1,
                const float* __restrict__ Mp, const float* __restrict__ Lp,
                ushort_t* __restrict__ AV)
{
    const int row = blockIdx.x;           // i*BSZ + b
    const int tid = threadIdx.x;
    const int i = row >> 1, b = row & 1;
    const int h = tid >> 4;
    const int bh = b * NH + h;
    const size_t mi = (size_t)bh * QLEN + i;
    const float m1 = Mp[mi],             l1 = Lp[mi];
    const float m2 = Mp[32 * QLEN + mi], l2 = Lp[32 * QLEN + mi];
    const float M = fmaxf(m1, m2);
    const float a1 = exp2f(m1 - M), a2 = exp2f(m2 - M);
    const float rl = 1.f / (l1 * a1 + l2 * a2);
    const float f1 = a1 * rl, f2 = a2 * rl;
    const float4 o1 = ((const float4*)(O0 + (size_t)row * DM))[tid];
    const float4 o2 = ((const float4*)(O1 + (size_t)row * DM))[tid];
    ushort_t* p = AV + (size_t)row * DM + tid * 4;
    p[0] = f2bf(o1.x * f1 + o2.x * f2);
    p[1] = f2bf(o1.y * f1 + o2.y * f2);
    p[2] = f2bf(o1.z * f1 + o2.z * f2);
    p[3] = f2bf(o1.w * f1 + o2.w * f2);
}

// ---------------------------------------------------------------------------
// out = LayerNorm(X + Y0 [+ Y1]); optional bf16 secondary output
// ---------------------------------------------------------------------------
__global__ __launch_bounds__(256)
void add_ln(const float* __restrict__ X, const float* __restrict__ Y0,
            const float* __restrict__ Y1,
            const float* __restrict__ gg, const float* __restrict__ bb,
            float* __restrict__ out, ushort_t* __restrict__ outb)
{
    const int row  = blockIdx.x;
    const int tid  = threadIdx.x;
    const int lane = tid & 63;
    const int w    = tid >> 6;
    __shared__ float ssum[4], ssq[4];

    const float4 xv = ((const float4*)(X + (size_t)row * DM))[tid];
    const float4 yv = ((const float4*)(Y0 + (size_t)row * DM))[tid];
    float v0 = xv.x + yv.x, v1 = xv.y + yv.y;
    float v2 = xv.z + yv.z, v3 = xv.w + yv.w;
    if (Y1) {
        const float4 zv = ((const float4*)(Y1 + (size_t)row * DM))[tid];
        v0 += zv.x; v1 += zv.y; v2 += zv.z; v3 += zv.w;
    }
    float s = v0 + v1 + v2 + v3;
    float q = v0 * v0 + v1 * v1 + v2 * v2 + v3 * v3;
#pragma unroll
    for (int off = 32; off > 0; off >>= 1) {
        s += __shfl_xor(s, off, 64);
        q += __shfl_xor(q, off, 64);
    }
    if (lane == 0) { ssum[w] = s; ssq[w] = q; }
    __syncthreads();
    s = ssum[0] + ssum[1] + ssum[2] + ssum[3];
    q = ssq[0] + ssq[1] + ssq[2] + ssq[3];
    const float mean = s * (1.f / DM);
    const float var  = q * (1.f / DM) - mean * mean;
    const float rs   = rsqrtf(var + 1e-5f);
    const float4 g4 = ((const float4*)gg)[tid];
    const float4 b4 = ((const float4*)bb)[tid];
    float4 ov;
    ov.x = (v0 - mean) * rs * g4.x + b4.x;
    ov.y = (v1 - mean) * rs * g4.y + b4.y;
    ov.z = (v2 - mean) * rs * g4.z + b4.z;
    ov.w = (v3 - mean) * rs * g4.w + b4.w;
    ((float4*)(out + (size_t)row * DM))[tid] = ov;
    if (outb) {
        ushort_t* p = outb + (size_t)row * DM + tid * 4;
        p[0] = f2bf(ov.x); p[1] = f2bf(ov.y);
        p[2] = f2bf(ov.z); p[3] = f2bf(ov.w);
    }
}

// ---------------------------------------------------------------------------
extern "C" void kernel_launch(void* const* d_in, const int* in_sizes, int n_in,
                              void* d_out, int out_size, void* d_ws, size_t ws_size,
                              hipStream_t stream)
{
    (void)in_sizes; (void)n_in; (void)out_size; (void)ws_size;
    const float* w      = (const float*)d_in[0];
    const float* r      = (const float*)d_in[1];
    const float* mems   = (const float*)d_in[2];
    // d_in[3] attn_mask: deterministic (j > i + MLEN), applied analytically
    const float* qkv_w  = (const float*)d_in[4];
    const float* rnet_w = (const float*)d_in[5];
    const float* o_w    = (const float*)d_in[6];
    const float* r_r_b  = (const float*)d_in[7];
    const float* r_w_b  = (const float*)d_in[8];
    const float* ln1g   = (const float*)d_in[9];
    const float* ln1b   = (const float*)d_in[10];
    const float* ffw1   = (const float*)d_in[11];
    const float* ffb1   = (const float*)d_in[12];
    const float* ffw2   = (const float*)d_in[13];
    const float* ffb2   = (const float*)d_in[14];
    const float* ln2g   = (const float*)d_in[15];
    const float* ln2b   = (const float*)d_in[16];
    float* out = (float*)d_out;

    char* wsb = (char*)d_ws;
    const size_t MB = 1024 * 1024;
    // ---- workspace layout, live ranges verified against launch order ----
    ushort_t* W1    = (ushort_t*)(wsb + 0 * MB);   // 0-6    dead after qkvr
    ushort_t* W2    = (ushort_t*)(wsb + 6 * MB);   // 6-8    dead after qkvr
    ushort_t* Acat  = (ushort_t*)(wsb + 8 * MB);   // 8-16   dead after qkvr
    ushort_t* Rsrc  = (ushort_t*)(wsb + 16 * MB);  // 16-20  dead after qkvr
    ushort_t* Qac   = (ushort_t*)(wsb + 20 * MB);  // 20-24  dead after attn
    ushort_t* Qbd   = (ushort_t*)(wsb + 24 * MB);  // 24-28  dead after attn
    ushort_t* Kbf   = (ushort_t*)(wsb + 28 * MB);  // 28-36  dead after attn
    ushort_t* Vt    = (ushort_t*)(wsb + 36 * MB);  // 36-44  dead after attn
    ushort_t* Rh    = (ushort_t*)(wsb + 44 * MB);  // 44-48  dead after attn
    float*    Op0   = (float*)(wsb + 48 * MB);     // 48-56  attn -> merge
    float*    Op1   = (float*)(wsb + 56 * MB);     // 56-64  attn -> merge
    float*    Mp    = (float*)(wsb + 4 * MB);      // 4-4.25 (over dead W1)
    float*    Lp    = (float*)(wsb + 4 * MB + 512 * 1024); // 4.5-4.75
    ushort_t* AVec  = (ushort_t*)(wsb + 0 * MB);   // 0-4   merge -> o-proj
    ushort_t* W3    = (ushort_t*)(wsb + 4 * MB);   // 4-6   cast2 -> o-proj (over Mp/Lp dead)
    float*    AOut0 = (float*)(wsb + 8 * MB);      // 8-16  o-proj -> ln1 (over Acat dead)
    float*    AOut1 = (float*)(wsb + 44 * MB);     // 44-52 o-proj -> ln1 (over Rh/Op0-head dead)
    float*    Hbuf  = (float*)(wsb + 16 * MB);     // 16-24 ln1 -> ln2 (over Rsrc/Qac dead)
    ushort_t* Hbf   = (ushort_t*)(wsb + 24 * MB);  // 24-28 ln1 -> ff1 (over Qbd dead)
    ushort_t* W4    = (ushort_t*)(wsb + 28 * MB);  // 28-36 cast2 -> ff1 (over Kbf dead)
    ushort_t* FFbf  = (ushort_t*)(wsb + 36 * MB);  // 36-52 ff1 -> ff2 (over Vt/AOut1 dead)
    ushort_t* W5    = (ushort_t*)(wsb + 52 * MB);  // 52-60 cast2 -> ff2 (over Op0-tail/Op1-head dead)
    float*    Core0 = (float*)(wsb + 0 * MB);      // 0-8   ff2 -> ln2 (AVec/W3 dead)
    float*    Core1 = (float*)(wsb + 8 * MB);      // 8-16  ff2 -> ln2 (AOut0 dead)
    // peak 64 MB

    dim3 blk(256);

    // casts for phase 1
    cast_phase1<<<dim3(5120), blk, 0, stream>>>(qkv_w, rnet_w, mems, w, r,
                                                W1, W2, Acat, Rsrc);

    // 1+2. fused QKV + r_net projections
    gemm_qkvr<<<dim3(896), blk, 0, stream>>>(
        Acat, W1, Rsrc, W2, Qac, Qbd, Kbf, Vt, Rh, r_w_b, r_r_b);

    // 3. MFMA flash attention, split-K x2 (contiguous halves) -> partials
    attn_mfma<<<dim3(16, 2, 32), blk, 0, stream>>>(
        Qac, Qbd, Kbf, Vt, Rh, Op0, Op1, Mp, Lp);

    // 3b. merge partials -> bf16 attn_vec
    attn_merge<<<dim3(2048), blk, 0, stream>>>(Op0, Op1, Mp, Lp, AVec);

    // casts for phase 2
    cast_phase2<<<dim3(4608), blk, 0, stream>>>(o_w, ffw1, ffw2, W3, W4, W5);

    // 4. output projection, split-K x2 (f32 partials)
    gemm_mfma<0, 0, 64, 2><<<dim3(16, 16, 2), blk, 0, stream>>>(
        AVec, W3, nullptr, AOut0, AOut1, 2048, 1024, 512, 1024, 1024);

    // 5. h = LN(w + AOut0 + AOut1)  (f32 + bf16 copies)
    add_ln<<<dim3(2 * QLEN), blk, 0, stream>>>(w, AOut0, AOut1, ln1g, ln1b, Hbuf, Hbf);

    // 6. FF1: relu(h @ ff_w1^T + b1) -> bf16
    gemm_mfma<3, 1, 128, 1><<<dim3(16, 32), blk, 0, stream>>>(
        Hbf, W4, ffb1, FFbf, nullptr, 2048, 4096, 1024, 1024, 1024);

    // 7. FF2, split-K x2 -> f32 partials
    gemm_mfma<0, 0, 64, 2><<<dim3(16, 16, 2), blk, 0, stream>>>(
        FFbf, W5, ffb2, Core0, Core1, 2048, 1024, 2048, 4096, 4096);

    // 8. out = LN(h + Core0 + Core1)
    add_ln<<<dim3(2 * QLEN), blk, 0, stream>>>(Hbuf, Core0, Core1, ln2g, ln2b, out, nullptr);
}

// Round 6
// 384.250 us; speedup vs baseline: 1.1784x; 1.0184x over previous
//
#include <hip/hip_runtime.h>
#include <math.h>

#define QLEN 1024
#define MLEN 1024
#define KLEN 2048
#define BSZc 2
#define NH 16
#define DH 64
#define DM 1024
#define DI 4096

typedef unsigned short ushort_t;
typedef __attribute__((ext_vector_type(8))) short short8;
typedef __attribute__((ext_vector_type(4))) float f32x4;

__device__ __forceinline__ ushort_t f2bf(float x) {
    unsigned int u = __float_as_uint(x);
    unsigned int r = (u + 0x7FFFu + ((u >> 16) & 1u)) >> 16;
    return (ushort_t)r;
}

__device__ __forceinline__ void gload_lds16(const ushort_t* g, ushort_t* l) {
    __builtin_amdgcn_global_load_lds(
        (const __attribute__((address_space(1))) unsigned int*)g,
        (__attribute__((address_space(3))) unsigned int*)l,
        16, 0, 0);
}

// ---------------------------------------------------------------------------
// segmented f32 -> bf16 casts (one launch per phase)
// ---------------------------------------------------------------------------
__device__ __forceinline__ void cast8(const float* s, ushort_t* d, int g) {
    const float4 a = *(const float4*)(s + g * 8);
    const float4 b = *(const float4*)(s + g * 8 + 4);
    short8 o;
    o[0] = (short)f2bf(a.x); o[1] = (short)f2bf(a.y);
    o[2] = (short)f2bf(a.z); o[3] = (short)f2bf(a.w);
    o[4] = (short)f2bf(b.x); o[5] = (short)f2bf(b.y);
    o[6] = (short)f2bf(b.z); o[7] = (short)f2bf(b.w);
    *(short8*)(d + g * 8) = o;
}

__global__ __launch_bounds__(256)
void cast_phase1(const float* __restrict__ qkv_w, const float* __restrict__ rnet_w,
                 const float* __restrict__ mems, const float* __restrict__ w,
                 const float* __restrict__ r,
                 ushort_t* __restrict__ W1, ushort_t* __restrict__ W2,
                 ushort_t* __restrict__ Acat, ushort_t* __restrict__ Rsrc)
{
    int g = blockIdx.x * 256 + threadIdx.x;
    if (g < 393216)            { cast8(qkv_w,  W1,              g); }
    else if (g < 524288)       { cast8(rnet_w, W2,              g - 393216); }
    else if (g < 786432)       { cast8(mems,   Acat,            g - 524288); }
    else if (g < 1048576)      { cast8(w,      Acat + 2097152,  g - 786432); }
    else if (g < 1310720)      { cast8(r,      Rsrc,            g - 1048576); }
}

__global__ __launch_bounds__(256)
void cast_phase2(const float* __restrict__ o_w, const float* __restrict__ ffw1,
                 const float* __restrict__ ffw2,
                 ushort_t* __restrict__ W3, ushort_t* __restrict__ W4,
                 ushort_t* __restrict__ W5)
{
    int g = blockIdx.x * 256 + threadIdx.x;
    if (g < 131072)            { cast8(o_w,  W3, g); }
    else if (g < 655360)       { cast8(ffw1, W4, g - 131072); }
    else if (g < 1179648)      { cast8(ffw2, W5, g - 655360); }
}

// ---------------------------------------------------------------------------
// bf16 MFMA GEMM: C = A @ B^T. 128 x BN tile, BK=64 (two BK=32 buffer pairs).
// SPLIT>1: blockIdx.z selects K-slice; partial f32 out; bias only on z==0.
// EMODE 0: f32 out (+bias). EMODE 3: bf16 out (+bias, +relu if ACT).
// ---------------------------------------------------------------------------
template<int EMODE, int ACT, int BN, int SPLIT>
__global__ __launch_bounds__(256)
void gemm_mfma(const ushort_t* __restrict__ A, const ushort_t* __restrict__ B,
               const float* __restrict__ bias,
               void* __restrict__ O0v, void* __restrict__ O1v,
               int M, int N, int Ks, int lda, int ldb)
{
    constexpr int JT = BN / 32;
    __shared__ ushort_t At0[128 * 32];
    __shared__ ushort_t At1[128 * 32];
    __shared__ ushort_t Bt0[BN * 32];
    __shared__ ushort_t Bt1[BN * 32];

    const int tid  = threadIdx.x;
    const int lane = tid & 63;
    const int w    = tid >> 6;
    const int lr   = lane & 15;
    const int quad = lane >> 4;
    const int m0   = blockIdx.x * 128;
    const int n0   = blockIdx.y * BN;
    const int z    = (SPLIT > 1) ? (int)blockIdx.z : 0;
    const int kbase = z * Ks;
    const int wm0  = (w >> 1) * 64;
    const int wn0  = (w & 1) * (BN / 2);

    f32x4 acc[4][JT];
#pragma unroll
    for (int it = 0; it < 4; ++it)
#pragma unroll
        for (int jt = 0; jt < JT; ++jt) acc[it][jt] = (f32x4){0.f, 0.f, 0.f, 0.f};

    const int srow = lane >> 2;
    const int scol = (lane & 3) << 3;
    const ushort_t* Ag = A + (size_t)(m0 + w * 32 + srow) * lda + kbase + scol;
    ushort_t* a00 = At0 + (w * 32) * 32;
    ushort_t* a01 = At0 + (w * 32 + 16) * 32;
    ushort_t* a10 = At1 + (w * 32) * 32;
    ushort_t* a11 = At1 + (w * 32 + 16) * 32;
    const ushort_t* Bg;
    ushort_t *b00, *b01 = nullptr, *b10, *b11 = nullptr;
    if (BN == 128) {
        Bg  = B + (size_t)(n0 + w * 32 + srow) * ldb + kbase + scol;
        b00 = Bt0 + (w * 32) * 32;
        b01 = Bt0 + (w * 32 + 16) * 32;
        b10 = Bt1 + (w * 32) * 32;
        b11 = Bt1 + (w * 32 + 16) * 32;
    } else {
        Bg  = B + (size_t)(n0 + w * 16 + srow) * ldb + kbase + scol;
        b00 = Bt0 + (w * 16) * 32;
        b10 = Bt1 + (w * 16) * 32;
    }

    const ushort_t* Ato0 = At0 + (wm0 + lr) * 32 + quad * 8;
    const ushort_t* Ato1 = At1 + (wm0 + lr) * 32 + quad * 8;
    const ushort_t* Bto0 = Bt0 + (wn0 + lr) * 32 + quad * 8;
    const ushort_t* Bto1 = Bt1 + (wn0 + lr) * 32 + quad * 8;

    for (int k0 = 0; k0 < Ks; k0 += 64) {
        __syncthreads();
        gload_lds16(Ag + k0, a00);
        gload_lds16(Ag + (size_t)16 * lda + k0, a01);
        gload_lds16(Ag + k0 + 32, a10);
        gload_lds16(Ag + (size_t)16 * lda + k0 + 32, a11);
        if (BN == 128) {
            gload_lds16(Bg + k0, b00);
            gload_lds16(Bg + (size_t)16 * ldb + k0, b01);
            gload_lds16(Bg + k0 + 32, b10);
            gload_lds16(Bg + (size_t)16 * ldb + k0 + 32, b11);
        } else {
            gload_lds16(Bg + k0, b00);
            gload_lds16(Bg + k0 + 32, b10);
        }
        __syncthreads();

        short8 af[4], bf[JT];
#pragma unroll
        for (int it = 0; it < 4; ++it)
            af[it] = *(const short8*)(Ato0 + it * 16 * 32);
#pragma unroll
        for (int jt = 0; jt < JT; ++jt)
            bf[jt] = *(const short8*)(Bto0 + jt * 16 * 32);
#pragma unroll
        for (int it = 0; it < 4; ++it)
#pragma unroll
            for (int jt = 0; jt < JT; ++jt)
                acc[it][jt] = __builtin_amdgcn_mfma_f32_16x16x32_bf16(
                    af[it], bf[jt], acc[it][jt], 0, 0, 0);
#pragma unroll
        for (int it = 0; it < 4; ++it)
            af[it] = *(const short8*)(Ato1 + it * 16 * 32);
#pragma unroll
        for (int jt = 0; jt < JT; ++jt)
            bf[jt] = *(const short8*)(Bto1 + jt * 16 * 32);
#pragma unroll
        for (int it = 0; it < 4; ++it)
#pragma unroll
            for (int jt = 0; jt < JT; ++jt)
                acc[it][jt] = __builtin_amdgcn_mfma_f32_16x16x32_bf16(
                    af[it], bf[jt], acc[it][jt], 0, 0, 0);
    }

#pragma unroll
    for (int it = 0; it < 4; ++it)
#pragma unroll
        for (int jt = 0; jt < JT; ++jt)
#pragma unroll
            for (int rg = 0; rg < 4; ++rg) {
                const int m = m0 + wm0 + it * 16 + quad * 4 + rg;
                const int n = n0 + wn0 + jt * 16 + lr;
                float v = acc[it][jt][rg];
                if (EMODE == 0) {
                    float* dst = (float*)(z ? O1v : O0v);
                    if (bias && z == 0) v += bias[n];
                    dst[(size_t)m * N + n] = v;
                } else {
                    v += bias[n];
                    if (ACT == 1) v = fmaxf(v, 0.f);
                    ((ushort_t*)O0v)[(size_t)m * N + n] = f2bf(v);
                }
            }
}

// ---------------------------------------------------------------------------
// Fused QKV + r_net GEMM — BK=64 structure (two BK=32 buffer pairs,
// 32 MFMA per staging round). Epilogue scatter unchanged.
// ---------------------------------------------------------------------------
__global__ __launch_bounds__(256)
void gemm_qkvr(const ushort_t* __restrict__ Acat, const ushort_t* __restrict__ W1,
               const ushort_t* __restrict__ Rsrc, const ushort_t* __restrict__ W2,
               ushort_t* __restrict__ Qac, ushort_t* __restrict__ Qbd,
               ushort_t* __restrict__ Kbf, ushort_t* __restrict__ Vtb,
               ushort_t* __restrict__ Rh,
               const float* __restrict__ rwb, const float* __restrict__ rrb)
{
    __shared__ ushort_t At0[128 * 32];
    __shared__ ushort_t At1[128 * 32];
    __shared__ ushort_t Bt0[128 * 32];
    __shared__ ushort_t Bt1[128 * 32];

    const int bid  = blockIdx.x;
    const bool isr = bid >= 768;
    const ushort_t* A; const ushort_t* B; int m0, n0;
    if (!isr) { A = Acat; B = W1; m0 = (bid & 31) * 128; n0 = (bid >> 5) * 128; }
    else { int t = bid - 768; A = Rsrc; B = W2; m0 = (t & 15) * 128; n0 = (t >> 4) * 128; }
    const int K = 1024;

    const int tid  = threadIdx.x;
    const int lane = tid & 63;
    const int w    = tid >> 6;
    const int lr   = lane & 15;
    const int quad = lane >> 4;
    const int wm0  = (w >> 1) * 64;
    const int wn0  = (w & 1) * 64;

    f32x4 acc[4][4];
#pragma unroll
    for (int it = 0; it < 4; ++it)
#pragma unroll
        for (int jt = 0; jt < 4; ++jt) acc[it][jt] = (f32x4){0.f, 0.f, 0.f, 0.f};

    const int srow = lane >> 2;
    const int scol = (lane & 3) << 3;
    const ushort_t* Ag = A + (size_t)(m0 + w * 32 + srow) * K + scol;
    const ushort_t* Bg = B + (size_t)(n0 + w * 32 + srow) * K + scol;
    ushort_t* a00 = At0 + (w * 32) * 32;
    ushort_t* a01 = At0 + (w * 32 + 16) * 32;
    ushort_t* a10 = At1 + (w * 32) * 32;
    ushort_t* a11 = At1 + (w * 32 + 16) * 32;
    ushort_t* b00 = Bt0 + (w * 32) * 32;
    ushort_t* b01 = Bt0 + (w * 32 + 16) * 32;
    ushort_t* b10 = Bt1 + (w * 32) * 32;
    ushort_t* b11 = Bt1 + (w * 32 + 16) * 32;

    const ushort_t* Ato0 = At0 + (wm0 + lr) * 32 + quad * 8;
    const ushort_t* Ato1 = At1 + (wm0 + lr) * 32 + quad * 8;
    const ushort_t* Bto0 = Bt0 + (wn0 + lr) * 32 + quad * 8;
    const ushort_t* Bto1 = Bt1 + (wn0 + lr) * 32 + quad * 8;

    for (int k0 = 0; k0 < K; k0 += 64) {
        __syncthreads();
        gload_lds16(Ag + k0, a00);
        gload_lds16(Ag + (size_t)16 * K + k0, a01);
        gload_lds16(Ag + k0 + 32, a10);
        gload_lds16(Ag + (size_t)16 * K + k0 + 32, a11);
        gload_lds16(Bg + k0, b00);
        gload_lds16(Bg + (size_t)16 * K + k0, b01);
        gload_lds16(Bg + k0 + 32, b10);
        gload_lds16(Bg + (size_t)16 * K + k0 + 32, b11);
        __syncthreads();

        short8 af[4], bf[4];
#pragma unroll
        for (int it = 0; it < 4; ++it)
            af[it] = *(const short8*)(Ato0 + it * 16 * 32);
#pragma unroll
        for (int jt = 0; jt < 4; ++jt)
            bf[jt] = *(const short8*)(Bto0 + jt * 16 * 32);
#pragma unroll
        for (int it = 0; it < 4; ++it)
#pragma unroll
            for (int jt = 0; jt < 4; ++jt)
                acc[it][jt] = __builtin_amdgcn_mfma_f32_16x16x32_bf16(
                    af[it], bf[jt], acc[it][jt], 0, 0, 0);
#pragma unroll
        for (int it = 0; it < 4; ++it)
            af[it] = *(const short8*)(Ato1 + it * 16 * 32);
#pragma unroll
        for (int jt = 0; jt < 4; ++jt)
            bf[jt] = *(const short8*)(Bto1 + jt * 16 * 32);
#pragma unroll
        for (int it = 0; it < 4; ++it)
#pragma unroll
            for (int jt = 0; jt < 4; ++jt)
                acc[it][jt] = __builtin_amdgcn_mfma_f32_16x16x32_bf16(
                    af[it], bf[jt], acc[it][jt], 0, 0, 0);
    }

#pragma unroll
    for (int it = 0; it < 4; ++it)
#pragma unroll
        for (int jt = 0; jt < 4; ++jt)
#pragma unroll
            for (int rg = 0; rg < 4; ++rg) {
                const int m = m0 + wm0 + it * 16 + quad * 4 + rg;
                const int n = n0 + wn0 + jt * 16 + lr;
                const float v = acc[it][jt][rg];
                if (!isr) {
                    const int j = m >> 1, b = m & 1;
                    const int part = n >> 10, hh = (n >> 6) & 15, d = n & 63;
                    if (part == 0) {
                        if (j >= MLEN) {
                            const int qi = j - MLEN;
                            const size_t qidx = (((size_t)(b * NH + hh)) * QLEN + qi) * DH + d;
                            Qac[qidx] = f2bf(v + rwb[hh * DH + d]);
                            Qbd[qidx] = f2bf(v + rrb[hh * DH + d]);
                        }
                    } else if (part == 1) {
                        Kbf[(((size_t)(b * NH + hh)) * KLEN + j) * DH + d] = f2bf(v);
                    } else {
                        Vtb[(((size_t)(b * NH + hh)) * DH + d) * KLEN + j] = f2bf(v);
                    }
                } else {
                    const int hh = n >> 6, d = n & 63;
                    Rh[(((size_t)hh) * KLEN + m) * DH + d] = f2bf(v);
                }
            }
}

// ---------------------------------------------------------------------------
// MFMA flash attention with TransformerXL rel-shift, split-K x2 (contiguous
// halves so the R window slides 64/chunk -> ring buffer).
//
// Round-6: + bijective XCD swizzle (T1). Logical order L = bh*32 + s*16 + qt;
// dispatch d -> XCD d%8 (HW round-robin) -> L = (d&7)*128 + (d>>3): each XCD
// owns 4 consecutive bh -> K/V/R working set ~3 MB fits its 4 MB L2
// (round-5 FETCH was 131 MB vs 28 MB unique = 4.7x HBM overfetch from
// same-bh blocks sprayed across all 8 XCDs). qt flipped so longest blocks
// (most chunks) dispatch first.
//
// Staging (verified round-4): wave-uniform global_load_lds dest; per-lane
// global row = base + lane>>3, source granule (lane&7)^(lane>>3) = T21
// source-side XOR swizzle; fragment reads XOR the same key.
// Schedule (2 barriers/chunk): barrier vmcnt(0) drains ARE the gloads'
// completion points:
//   B -> issue V gload(c) -> BD/AC/softmax (covers V latency) -> C
//     -> issue K/R gload(c+1) -> PV(c) (covers K/R latency) -> loop
// LDS = Kt 8192 + Rt 16384 + Vl 8192 + Bw 21504 = 54272 B -> 3 blocks/CU.
// ---------------------------------------------------------------------------
__global__ __launch_bounds__(256, 3)
void attn_mfma(const ushort_t* __restrict__ Qac, const ushort_t* __restrict__ Qbd,
               const ushort_t* __restrict__ Kb, const ushort_t* __restrict__ Vt,
               const ushort_t* __restrict__ Rb,
               float* __restrict__ Op0, float* __restrict__ Op1,
               float* __restrict__ Mp, float* __restrict__ Lp)
{
    __shared__ __align__(16) ushort_t Kt[64 * 64];     //  8192 B, swizzled
    __shared__ __align__(16) ushort_t Rt[128 * 64];    // 16384 B, ring, swizzled
    __shared__ __align__(16) ushort_t Vl[64 * 64];     //  8192 B, swizzled
    __shared__ __align__(16) float    Bw[4][16][84];   // 21504 B

    const int tid  = threadIdx.x;
    const int lane = tid & 63;
    const int w    = tid >> 6;
    const int lr   = lane & 15;
    const int quad = lane >> 4;
    // XCD swizzle: dispatch d -> logical L; XCD (d%8) owns bh in [4*(d%8), ...)
    const int d    = blockIdx.x;
    const int L    = (d & 7) * 128 + (d >> 3);
    const int qt   = 15 - (L & 15);         // longest blocks first
    const int s    = (L >> 4) & 1;
    const int bh   = L >> 5;
    const int i0   = qt << 6;
    const int h    = bh & 15;
    const int b    = bh >> 4;

    short8 qaf[2], qbf[2];
    {
        const size_t rowoff = ((size_t)bh * QLEN + i0 + w * 16 + lr) * DH;
#pragma unroll
        for (int kt = 0; kt < 2; ++kt) {
            qaf[kt] = *(const short8*)(Qac + rowoff + kt * 32 + quad * 8);
            qbf[kt] = *(const short8*)(Qbd + rowoff + kt * 32 + quad * 8);
        }
    }

    f32x4 O[4];
#pragma unroll
    for (int nt = 0; nt < 4; ++nt) O[nt] = (f32x4){0.f, 0.f, 0.f, 0.f};
    float m_run = -3.4e38f, l_run = 0.f;

    const int nc   = qt + 17;
    const int half = (nc + 1) >> 1;
    const int c_lo = s ? half : 0;
    const int c_hi = s ? nc : half;
    const int stw  = 3 - w;
    const float SC = 0.125f * 1.44269504f;   // scale * log2(e)
    const ushort_t* Kh  = Kb + (size_t)bh * KLEN * DH;
    const ushort_t* Vh  = Vt + (size_t)bh * DH * KLEN;
    const ushort_t* Rhp = Rb + (size_t)h * KLEN * DH;

    // per-lane staging coords (global side); LDS dest stays wave-uniform
    const int lrow = lane >> 3;          // 0..7: row within the wave's 8-row block
    const int lsg  = lane & 7;           // dest granule -> source granule lsg^lrow
    const int sgo  = (lsg ^ lrow) << 3;  // source col offset (ushorts)
    // fragment-read granule offsets (ushorts)
    const int xq   = lr & 7;
    const int fo0  = ((quad ^ xq)) << 3;
    const int fo1  = (((4 | quad) ^ xq)) << 3;

    // ---- prologue: stage K[c_lo] + full 128-row R ring ----
    {
        const int j0 = c_lo << 6;
        const int wb = 960 - i0 + j0;
#pragma unroll
        for (int t = 0; t < 2; ++t) {
            const int rb  = t * 32 + w * 8;           // uniform row base
            gload_lds16(Kh + (size_t)(j0 + rb + lrow) * DH + sgo,
                        Kt + rb * 64);
        }
#pragma unroll
        for (int t = 0; t < 4; ++t) {
            const int gb = wb + t * 32 + w * 8;       // uniform global row base
            const int g  = gb + lrow;
            const int gc = g > (KLEN - 1) ? (KLEN - 1) : g;  // clamped rows feed only masked cells
            gload_lds16(Rhp + (size_t)gc * DH + sgo,
                        Rt + (gb & 127) * 64);
        }
    }

    for (int c = c_lo; c < c_hi; ++c) {
        const int j0 = c << 6;
        const int wb = 960 - i0 + j0;      // window base (global R row of wr=0)

        __syncthreads();   // B: K/R gloads drained -> staging visible

        // issue THIS chunk's V gload (Vl free: PV(c-1) done before B);
        // latency hides under BD/AC/softmax, drained at barrier C
#pragma unroll
        for (int t = 0; t < 2; ++t) {
            const int db = t * 32 + w * 8;            // uniform row base
            gload_lds16(Vh + (size_t)(db + lrow) * KLEN + j0 + sgo,
                        Vl + db * 64);
        }

        // BD: 5 window col-tiles -> Bw (f32)
#pragma unroll
        for (int ctl = 0; ctl < 5; ++ctl) {
            const int wr = (stw + ctl) * 16 + lr;
            const int ring = (wb + wr) & 127;
            f32x4 z = (f32x4){0.f, 0.f, 0.f, 0.f};
            short8 r0 = *(const short8*)&Rt[ring * 64 + fo0];
            z = __builtin_amdgcn_mfma_f32_16x16x32_bf16(qbf[0], r0, z, 0, 0, 0);
            short8 r1 = *(const short8*)&Rt[ring * 64 + fo1];
            z = __builtin_amdgcn_mfma_f32_16x16x32_bf16(qbf[1], r1, z, 0, 0, 0);
#pragma unroll
            for (int rg = 0; rg < 4; ++rg)
                Bw[w][quad * 4 + rg][ctl * 16 + lr] = z[rg];
        }
        // AC: add at shifted col jj + 15 - row
#pragma unroll
        for (int ct = 0; ct < 4; ++ct) {
            f32x4 z = (f32x4){0.f, 0.f, 0.f, 0.f};
            short8 k0f = *(const short8*)&Kt[(ct * 16 + lr) * 64 + fo0];
            z = __builtin_amdgcn_mfma_f32_16x16x32_bf16(qaf[0], k0f, z, 0, 0, 0);
            short8 k1f = *(const short8*)&Kt[(ct * 16 + lr) * 64 + fo1];
            z = __builtin_amdgcn_mfma_f32_16x16x32_bf16(qaf[1], k1f, z, 0, 0, 0);
#pragma unroll
            for (int rg = 0; rg < 4; ++rg) {
                const int rrow = quad * 4 + rg;
                Bw[w][rrow][ct * 16 + lr + 15 - rrow] += z[rg];
            }
        }

        // online softmax; lane's 16 probs == its PV A-fragment
        const int lim = i0 + w * 16 + lr + 1024 - j0;
        float pv[16];
        float mx = -3.4e38f;
#pragma unroll
        for (int kt = 0; kt < 2; ++kt)
#pragma unroll
            for (int t = 0; t < 8; ++t) {
                const int jj = kt * 32 + quad * 8 + t;
                float sv = Bw[w][lr][jj + 15 - lr] * SC;
                sv = (jj > lim) ? -3.4e38f : sv;
                pv[kt * 8 + t] = sv;
                mx = fmaxf(mx, sv);
            }
        mx = fmaxf(mx, __shfl_xor(mx, 16, 64));
        mx = fmaxf(mx, __shfl_xor(mx, 32, 64));
        const float m_new = fmaxf(m_run, mx);
        float ps = 0.f;
        short8 pf[2];
#pragma unroll
        for (int kt = 0; kt < 2; ++kt)
#pragma unroll
            for (int t = 0; t < 8; ++t) {
                const float e = exp2f(pv[kt * 8 + t] - m_new);
                ps += e;
                pf[kt][t] = (short)f2bf(e);
            }
        ps += __shfl_xor(ps, 16, 64);
        ps += __shfl_xor(ps, 32, 64);
        const float alpha = exp2f(m_run - m_new);
        m_run = m_new;
        l_run = l_run * alpha + ps;

        __syncthreads();   // C: V gload drained; Bw/Kt/Rt reads done

        // issue NEXT chunk's K + new R ring rows (Kt readers and the target
        // ring slots' readers finished at C); latency hides under PV,
        // drained at next barrier B
        if (c + 1 < c_hi) {
            const int j1 = j0 + 64;
#pragma unroll
            for (int t = 0; t < 2; ++t) {
                const int rb = t * 32 + w * 8;
                gload_lds16(Kh + (size_t)(j1 + rb + lrow) * DH + sgo,
                            Kt + rb * 64);
            }
#pragma unroll
            for (int t = 0; t < 2; ++t) {
                const int gb = wb + 128 + t * 32 + w * 8;
                const int g  = gb + lrow;
                const int gc = g > (KLEN - 1) ? (KLEN - 1) : g;
                gload_lds16(Rhp + (size_t)gc * DH + sgo,
                            Rt + (gb & 127) * 64);
            }
        }

        float ar[4];
#pragma unroll
        for (int rg = 0; rg < 4; ++rg)
            ar[rg] = __shfl(alpha, quad * 4 + rg, 64);
#pragma unroll
        for (int nt = 0; nt < 4; ++nt) {
            O[nt][0] *= ar[0]; O[nt][1] *= ar[1];
            O[nt][2] *= ar[2]; O[nt][3] *= ar[3];
        }
        {
            short8 vb;
#pragma unroll
            for (int nt = 0; nt < 4; ++nt) {
                vb = *(const short8*)&Vl[(nt * 16 + lr) * 64 + fo0];
                O[nt] = __builtin_amdgcn_mfma_f32_16x16x32_bf16(pf[0], vb, O[nt], 0, 0, 0);
            }
#pragma unroll
            for (int nt = 0; nt < 4; ++nt) {
                vb = *(const short8*)&Vl[(nt * 16 + lr) * 64 + fo1];
                O[nt] = __builtin_amdgcn_mfma_f32_16x16x32_bf16(pf[1], vb, O[nt], 0, 0, 0);
            }
        }
    }

    if (quad == 0) {
        const size_t mi = ((size_t)s * 32 + bh) * QLEN + i0 + w * 16 + lr;
        Mp[mi] = m_run;
        Lp[mi] = l_run;
    }
    float* Op = s ? Op1 : Op0;
#pragma unroll
    for (int nt = 0; nt < 4; ++nt)
#pragma unroll
        for (int rg = 0; rg < 4; ++rg) {
            const int i = i0 + w * 16 + quad * 4 + rg;
            Op[((size_t)i * BSZc + b) * DM + h * DH + nt * 16 + lr] = O[nt][rg];
        }
}

// ---------------------------------------------------------------------------
// merge split-K partials -> bf16 attn_vec
// ---------------------------------------------------------------------------
__global__ __launch_bounds__(256)
void attn_merge(const float* __restrict__ O0, const float* __restrict__ O1,
                const float* __restrict__ Mp, const float* __restrict__ Lp,
                ushort_t* __restrict__ AV)
{
    const int row = blockIdx.x;           // i*BSZ + b
    const int tid = threadIdx.x;
    const int i = row >> 1, b = row & 1;
    const int h = tid >> 4;
    const int bh = b * NH + h;
    const size_t mi = (size_t)bh * QLEN + i;
    const float m1 = Mp[mi],             l1 = Lp[mi];
    const float m2 = Mp[32 * QLEN + mi], l2 = Lp[32 * QLEN + mi];
    const float M = fmaxf(m1, m2);
    const float a1 = exp2f(m1 - M), a2 = exp2f(m2 - M);
    const float rl = 1.f / (l1 * a1 + l2 * a2);
    const float f1 = a1 * rl, f2 = a2 * rl;
    const float4 o1 = ((const float4*)(O0 + (size_t)row * DM))[tid];
    const float4 o2 = ((const float4*)(O1 + (size_t)row * DM))[tid];
    ushort_t* p = AV + (size_t)row * DM + tid * 4;
    p[0] = f2bf(o1.x * f1 + o2.x * f2);
    p[1] = f2bf(o1.y * f1 + o2.y * f2);
    p[2] = f2bf(o1.z * f1 + o2.z * f2);
    p[3] = f2bf(o1.w * f1 + o2.w * f2);
}

// ---------------------------------------------------------------------------
// out = LayerNorm(X + Y0 [+ Y1]); optional bf16 secondary output
// ---------------------------------------------------------------------------
__global__ __launch_bounds__(256)
void add_ln(const float* __restrict__ X, const float* __restrict__ Y0,
            const float* __restrict__ Y1,
            const float* __restrict__ gg, const float* __restrict__ bb,
            float* __restrict__ out, ushort_t* __restrict__ outb)
{
    const int row  = blockIdx.x;
    const int tid  = threadIdx.x;
    const int lane = tid & 63;
    const int w    = tid >> 6;
    __shared__ float ssum[4], ssq[4];

    const float4 xv = ((const float4*)(X + (size_t)row * DM))[tid];
    const float4 yv = ((const float4*)(Y0 + (size_t)row * DM))[tid];
    float v0 = xv.x + yv.x, v1 = xv.y + yv.y;
    float v2 = xv.z + yv.z, v3 = xv.w + yv.w;
    if (Y1) {
        const float4 zv = ((const float4*)(Y1 + (size_t)row * DM))[tid];
        v0 += zv.x; v1 += zv.y; v2 += zv.z; v3 += zv.w;
    }
    float s = v0 + v1 + v2 + v3;
    float q = v0 * v0 + v1 * v1 + v2 * v2 + v3 * v3;
#pragma unroll
    for (int off = 32; off > 0; off >>= 1) {
        s += __shfl_xor(s, off, 64);
        q += __shfl_xor(q, off, 64);
    }
    if (lane == 0) { ssum[w] = s; ssq[w] = q; }
    __syncthreads();
    s = ssum[0] + ssum[1] + ssum[2] + ssum[3];
    q = ssq[0] + ssq[1] + ssq[2] + ssq[3];
    const float mean = s * (1.f / DM);
    const float var  = q * (1.f / DM) - mean * mean;
    const float rs   = rsqrtf(var + 1e-5f);
    const float4 g4 = ((const float4*)gg)[tid];
    const float4 b4 = ((const float4*)bb)[tid];
    float4 ov;
    ov.x = (v0 - mean) * rs * g4.x + b4.x;
    ov.y = (v1 - mean) * rs * g4.y + b4.y;
    ov.z = (v2 - mean) * rs * g4.z + b4.z;
    ov.w = (v3 - mean) * rs * g4.w + b4.w;
    ((float4*)(out + (size_t)row * DM))[tid] = ov;
    if (outb) {
        ushort_t* p = outb + (size_t)row * DM + tid * 4;
        p[0] = f2bf(ov.x); p[1] = f2bf(ov.y);
        p[2] = f2bf(ov.z); p[3] = f2bf(ov.w);
    }
}

// ---------------------------------------------------------------------------
extern "C" void kernel_launch(void* const* d_in, const int* in_sizes, int n_in,
                              void* d_out, int out_size, void* d_ws, size_t ws_size,
                              hipStream_t stream)
{
    (void)in_sizes; (void)n_in; (void)out_size; (void)ws_size;
    const float* w      = (const float*)d_in[0];
    const float* r      = (const float*)d_in[1];
    const float* mems   = (const float*)d_in[2];
    // d_in[3] attn_mask: deterministic (j > i + MLEN), applied analytically
    const float* qkv_w  = (const float*)d_in[4];
    const float* rnet_w = (const float*)d_in[5];
    const float* o_w    = (const float*)d_in[6];
    const float* r_r_b  = (const float*)d_in[7];
    const float* r_w_b  = (const float*)d_in[8];
    const float* ln1g   = (const float*)d_in[9];
    const float* ln1b   = (const float*)d_in[10];
    const float* ffw1   = (const float*)d_in[11];
    const float* ffb1   = (const float*)d_in[12];
    const float* ffw2   = (const float*)d_in[13];
    const float* ffb2   = (const float*)d_in[14];
    const float* ln2g   = (const float*)d_in[15];
    const float* ln2b   = (const float*)d_in[16];
    float* out = (float*)d_out;

    char* wsb = (char*)d_ws;
    const size_t MB = 1024 * 1024;
    // ---- workspace layout, live ranges verified against launch order ----
    ushort_t* W1    = (ushort_t*)(wsb + 0 * MB);   // 0-6    dead after qkvr
    ushort_t* W2    = (ushort_t*)(wsb + 6 * MB);   // 6-8    dead after qkvr
    ushort_t* Acat  = (ushort_t*)(wsb + 8 * MB);   // 8-16   dead after qkvr
    ushort_t* Rsrc  = (ushort_t*)(wsb + 16 * MB);  // 16-20  dead after qkvr
    ushort_t* Qac   = (ushort_t*)(wsb + 20 * MB);  // 20-24  dead after attn
    ushort_t* Qbd   = (ushort_t*)(wsb + 24 * MB);  // 24-28  dead after attn
    ushort_t* Kbf   = (ushort_t*)(wsb + 28 * MB);  // 28-36  dead after attn
    ushort_t* Vt    = (ushort_t*)(wsb + 36 * MB);  // 36-44  dead after attn
    ushort_t* Rh    = (ushort_t*)(wsb + 44 * MB);  // 44-48  dead after attn
    float*    Op0   = (float*)(wsb + 48 * MB);     // 48-56  attn -> merge
    float*    Op1   = (float*)(wsb + 56 * MB);     // 56-64  attn -> merge
    float*    Mp    = (float*)(wsb + 4 * MB);      // 4-4.25 (over dead W1)
    float*    Lp    = (float*)(wsb + 4 * MB + 512 * 1024); // 4.5-4.75
    ushort_t* AVec  = (ushort_t*)(wsb + 0 * MB);   // 0-4   merge -> o-proj
    ushort_t* W3    = (ushort_t*)(wsb + 4 * MB);   // 4-6   cast2 -> o-proj (over Mp/Lp dead)
    float*    AOut0 = (float*)(wsb + 8 * MB);      // 8-16  o-proj -> ln1 (over Acat dead)
    float*    AOut1 = (float*)(wsb + 44 * MB);     // 44-52 o-proj -> ln1 (over Rh/Op0-head dead)
    float*    Hbuf  = (float*)(wsb + 16 * MB);     // 16-24 ln1 -> ln2 (over Rsrc/Qac dead)
    ushort_t* Hbf   = (ushort_t*)(wsb + 24 * MB);  // 24-28 ln1 -> ff1 (over Qbd dead)
    ushort_t* W4    = (ushort_t*)(wsb + 28 * MB);  // 28-36 cast2 -> ff1 (over Kbf dead)
    ushort_t* FFbf  = (ushort_t*)(wsb + 36 * MB);  // 36-52 ff1 -> ff2 (over Vt/AOut1 dead)
    ushort_t* W5    = (ushort_t*)(wsb + 52 * MB);  // 52-60 cast2 -> ff2 (over Op0-tail/Op1-head dead)
    float*    Core0 = (float*)(wsb + 0 * MB);      // 0-8   ff2 -> ln2 (AVec/W3 dead)
    float*    Core1 = (float*)(wsb + 8 * MB);      // 8-16  ff2 -> ln2 (AOut0 dead)
    // peak 64 MB

    dim3 blk(256);

    // casts for phase 1
    cast_phase1<<<dim3(5120), blk, 0, stream>>>(qkv_w, rnet_w, mems, w, r,
                                                W1, W2, Acat, Rsrc);

    // 1+2. fused QKV + r_net projections
    gemm_qkvr<<<dim3(896), blk, 0, stream>>>(
        Acat, W1, Rsrc, W2, Qac, Qbd, Kbf, Vt, Rh, r_w_b, r_r_b);

    // 3. MFMA flash attention, split-K x2, XCD-swizzled 1D grid -> partials
    attn_mfma<<<dim3(1024), blk, 0, stream>>>(
        Qac, Qbd, Kbf, Vt, Rh, Op0, Op1, Mp, Lp);

    // 3b. merge partials -> bf16 attn_vec
    attn_merge<<<dim3(2048), blk, 0, stream>>>(Op0, Op1, Mp, Lp, AVec);

    // casts for phase 2
    cast_phase2<<<dim3(4608), blk, 0, stream>>>(o_w, ffw1, ffw2, W3, W4, W5);

    // 4. output projection, split-K x2 (f32 partials)
    gemm_mfma<0, 0, 64, 2><<<dim3(16, 16, 2), blk, 0, stream>>>(
        AVec, W3, nullptr, AOut0, AOut1, 2048, 1024, 512, 1024, 1024);

    // 5. h = LN(w + AOut0 + AOut1)  (f32 + bf16 copies)
    add_ln<<<dim3(2 * QLEN), blk, 0, stream>>>(w, AOut0, AOut1, ln1g, ln1b, Hbuf, Hbf);

    // 6. FF1: relu(h @ ff_w1^T + b1) -> bf16
    gemm_mfma<3, 1, 128, 1><<<dim3(16, 32), blk, 0, stream>>>(
        Hbf, W4, ffb1, FFbf, nullptr, 2048, 4096, 1024, 1024, 1024);

    // 7. FF2, split-K x2 -> f32 partials
    gemm_mfma<0, 0, 64, 2><<<dim3(16, 16, 2), blk, 0, stream>>>(
        FFbf, W5, ffb2, Core0, Core1, 2048, 1024, 2048, 4096, 4096);

    // 8. out = LN(h + Core0 + Core1)
    add_ln<<<dim3(2 * QLEN), blk, 0, stream>>>(Hbuf, Core0, Core1, ln2g, ln2b, out, nullptr);
}